// Round 13
// baseline (546.156 us; speedup 1.0000x reference)
//
#include <hip/hip_runtime.h>
#include <stdint.h>

#define DI __device__ __forceinline__

constexpr int Bn = 32, Cc = 64, Wn = 96, Hn = 96, Ln = 32, NG = 128, OUTC = 256;
constexpr int SEQ = 96;
constexpr long long NPIX = (long long)Bn * Wn * Hn;   // 294912
constexpr int GRAM_BLOCKS = 256;
constexpr int PIX_PER_BLOCK = (int)(NPIX / GRAM_BLOCKS); // 1152

typedef __attribute__((ext_vector_type(8))) short bf16x8;
typedef __attribute__((ext_vector_type(4))) float f32x4;

constexpr float LOG2E  = 1.44269504088896340736f;
constexpr float TWOL2E = 2.88539008177792681472f;

DI float exp2_(float x) { return __builtin_amdgcn_exp2f(x); }   // v_exp_f32
DI float rcp_(float x)  { return __builtin_amdgcn_rcpf(x); }    // v_rcp_f32 (~1ulp)
DI float bf2f(unsigned short u) { return __uint_as_float(((unsigned)u) << 16); }
DI unsigned short f2bf(float f) {
    unsigned u = __float_as_uint(f);
    u += 0x7FFFu + ((u >> 16) & 1u);   // RNE
    return (unsigned short)(u >> 16);
}

union U32x4 { unsigned u[4]; bf16x8 v; };

// ---------------------------------------------------------------------------
// x transpose: [B,C,W,H] f32 -> xT[chain=(b,w)][t=h][c] bf16.
// ---------------------------------------------------------------------------
__global__ __launch_bounds__(256)
void transpose_x(const float* __restrict__ x, unsigned short* __restrict__ xT)
{
    __shared__ alignas(16) unsigned char xs[96 * 128];
    const int tid = threadIdx.x;
    const int b = blockIdx.x / 96, q = blockIdx.x % 96;
    for (int i = tid; i < 1536; i += 256) {
        int c = i / 24, h4 = i - c * 24;
        float4 v = *(const float4*)(x + (((size_t)b * 64 + c) * 96 + q) * 96 + 4 * h4);
        float vv[4] = {v.x, v.y, v.z, v.w};
#pragma unroll
        for (int j = 0; j < 4; ++j) {
            int h = 4 * h4 + j;
            *(unsigned short*)(xs + h * 128 + ((c * 2) ^ ((h & 7) << 4))) = f2bf(vv[j]);
        }
    }
    __syncthreads();
    unsigned short* ob = xT + (size_t)blockIdx.x * 6144;
    for (int i = tid; i < 768; i += 256) {
        int row = i >> 3, k8 = i & 7;
        bf16x8 p = *(const bf16x8*)(xs + row * 128 + ((k8 * 16) ^ ((row & 7) << 4)));
        *(bf16x8*)(ob + (size_t)i * 8) = p;
    }
}

// ---------------------------------------------------------------------------
// FUSED BiLSTM (R13 = R11's 2-unit interleave + R12's lean activations).
// R12 evidence: lstm ~85us/pass vs ~34us issue floor (per-step wall ~2125cyc
// vs ~1000cyc pipe occupancy) -> ~50% dependency stall (exp2->rcp chains,
// shfl->MFMA latency), zero TLP (1 wave/SIMD). R11's 2-unit failed ONLY
// because div-serialization saturated issue (1.75x time); with lean
// activations the second unit fills the stall cycles.
// Two units per wave (groups g, g+96; same dir -> SHARED weight regs):
//   P(t+1): 16 h-independent MFMAs (Wih@x, bias C-in) -> xac bank
//   R(t):   8 shfl (h) -> 8 dependent MFMA -> exp2-domain activations -> store
// Weights pre-scaled by log2e (g-gate tiles by 2*log2e). Grid 192 x 1 wave.
// ---------------------------------------------------------------------------
#define FLOADU(UN, XA, XB, STI)                                                \
    if ((STI) < 96) {                                                          \
        const int tl_ = dir ? 95 - (STI) : (STI);                              \
        XA = *(const bf16x8*)(xTb##UN + (size_t)tl_ * 64);                     \
        XB = *(const bf16x8*)(xTb##UN + (size_t)tl_ * 64 + 32);                \
    }

#define PPROJ(UN, XA, XB)                                                      \
    _Pragma("unroll")                                                          \
    for (int tt = 0; tt < 8; ++tt) {                                           \
        f32x4 tp_ = __builtin_amdgcn_mfma_f32_16x16x32_bf16(ax0[tt], XA, bc[tt], 0, 0, 0); \
        xac##UN[tt] = __builtin_amdgcn_mfma_f32_16x16x32_bf16(ax1[tt], XB, tp_, 0, 0, 0);  \
    }

#define RSTEP(UN, STI)                                                         \
    {                                                                          \
        const int t_ = dir ? 95 - (STI) : (STI);                               \
        U32x4 hu;                                                              \
        {                                                                      \
            int a0 = __shfl((int)pk0x##UN, srcL0), a1 = __shfl((int)pk0y##UN, srcL0); \
            int a2 = __shfl((int)pk0x##UN, srcL1), a3 = __shfl((int)pk0y##UN, srcL1); \
            int b0 = __shfl((int)pk1x##UN, srcL0), b1 = __shfl((int)pk1y##UN, srcL0); \
            int b2 = __shfl((int)pk1x##UN, srcL1), b3 = __shfl((int)pk1y##UN, srcL1); \
            hu.u[0] = sp ? (unsigned)b0 : (unsigned)a0;                        \
            hu.u[1] = sp ? (unsigned)b1 : (unsigned)a1;                        \
            hu.u[2] = sp ? (unsigned)b2 : (unsigned)a2;                        \
            hu.u[3] = sp ? (unsigned)b3 : (unsigned)a3;                        \
        }                                                                      \
        f32x4 ac_[8];                                                          \
        _Pragma("unroll")                                                      \
        for (int tt = 0; tt < 8; ++tt)                                         \
            ac_[tt] = __builtin_amdgcn_mfma_f32_16x16x32_bf16(ah[tt], hu.v, xac##UN[tt], 0, 0, 0); \
        _Pragma("unroll")                                                      \
        for (int s = 0; s < 2; ++s) {                                          \
            unsigned short hs[4];                                              \
            _Pragma("unroll")                                                  \
            for (int j = 0; j < 4; ++j) {                                      \
                const float iv = rcp_(1.f + exp2_(-ac_[0 + s][j]));            \
                const float fv = rcp_(1.f + exp2_(-ac_[2 + s][j]));            \
                const float gr = rcp_(1.f + exp2_(-ac_[4 + s][j]));            \
                const float gv = fmaf(2.f, gr, -1.f);                          \
                const float ov = rcp_(1.f + exp2_(-ac_[6 + s][j]));            \
                cc##UN[s][j] = fmaf(fv, cc##UN[s][j], iv * gv);                \
                const float r_ = rcp_(exp2_(cc##UN[s][j] * TWOL2E) + 1.f);     \
                const float t2 = -2.f * ov;                                    \
                hs[j] = f2bf(fmaf(t2, r_, ov));                                \
            }                                                                  \
            const unsigned dlo = ((unsigned)hs[1] << 16) | hs[0];              \
            const unsigned dhi = ((unsigned)hs[3] << 16) | hs[2];              \
            if (s == 0) { pk0x##UN = dlo; pk0y##UN = dhi; }                    \
            else        { pk1x##UN = dlo; pk1y##UN = dhi; }                    \
            ushort4 hp; hp.x = hs[0]; hp.y = hs[1]; hp.z = hs[2]; hp.w = hs[3];\
            const int cbase = dir * 32 + s * 16 + rg * 4;                      \
            const size_t oidx = VERT                                           \
                ? ((((size_t)b##UN * 96 + t_) * 96 + q##UN) * 64 + cbase)      \
                : ((((size_t)b##UN * 96 + q##UN) * 96 + t_) * 64 + cbase);     \
            *(ushort4*)(outU + oidx) = hp;                                     \
        }                                                                      \
    }

template<int VERT>
__global__ __launch_bounds__(64, 1)
void lstm_fused(const unsigned short* __restrict__ xT,
                const float* __restrict__ wih_f, const float* __restrict__ whh_f,
                const float* __restrict__ bih_f, const float* __restrict__ bhh_f,
                const float* __restrict__ wih_b, const float* __restrict__ whh_b,
                const float* __restrict__ bih_b, const float* __restrict__ bhh_b,
                unsigned short* __restrict__ outU)
{
    const int lane = threadIdx.x;
    const int dir = blockIdx.x & 1, gpair = blockIdx.x >> 1;   // gpair in [0,96)
    const int n_ = lane & 15, rg = lane >> 4;

    // unit A = group gpair, unit B = group gpair+96 (same dir -> shared weights)
    const int gA = gpair, gB = gpair + 96;
    const int chainA = gA * 16 + n_, chainB = gB * 16 + n_;
    const int bA = gA / 6, qA = (gA % 6) * 16 + n_;
    const int bB = gB / 6, qB = (gB % 6) * 16 + n_;

    const float* wih = dir ? wih_b : wih_f;
    const float* whh = dir ? whh_b : whh_f;
    const float* bih = dir ? bih_b : bih_f;
    const float* bhh = dir ? bhh_b : bhh_f;

    // Weight fragments, pre-scaled into exp2 domain (g-gate tiles 4,5 by
    // 2*log2e). Mapping refcheck'd R9-R12. lane (n_, rg): row = tt*16+n_,
    // k = rg*8..+8.
    bf16x8 ah[8], ax0[8], ax1[8];
    f32x4 bc[8];
#pragma unroll
    for (int tt = 0; tt < 8; ++tt) {
        const float sc = (tt == 4 || tt == 5) ? TWOL2E : LOG2E;
        const float* sh = whh + (size_t)(tt * 16 + n_) * 32 + rg * 8;
        const float* sx = wih + (size_t)(tt * 16 + n_) * 64 + rg * 8;
        float4 h0 = *(const float4*)sh, h1 = *(const float4*)(sh + 4);
        float4 x0 = *(const float4*)sx, x1 = *(const float4*)(sx + 4);
        float4 x2 = *(const float4*)(sx + 32), x3 = *(const float4*)(sx + 36);
        ah[tt][0] = (short)f2bf(sc * h0.x); ah[tt][1] = (short)f2bf(sc * h0.y);
        ah[tt][2] = (short)f2bf(sc * h0.z); ah[tt][3] = (short)f2bf(sc * h0.w);
        ah[tt][4] = (short)f2bf(sc * h1.x); ah[tt][5] = (short)f2bf(sc * h1.y);
        ah[tt][6] = (short)f2bf(sc * h1.z); ah[tt][7] = (short)f2bf(sc * h1.w);
        ax0[tt][0] = (short)f2bf(sc * x0.x); ax0[tt][1] = (short)f2bf(sc * x0.y);
        ax0[tt][2] = (short)f2bf(sc * x0.z); ax0[tt][3] = (short)f2bf(sc * x0.w);
        ax0[tt][4] = (short)f2bf(sc * x1.x); ax0[tt][5] = (short)f2bf(sc * x1.y);
        ax0[tt][6] = (short)f2bf(sc * x1.z); ax0[tt][7] = (short)f2bf(sc * x1.w);
        ax1[tt][0] = (short)f2bf(sc * x2.x); ax1[tt][1] = (short)f2bf(sc * x2.y);
        ax1[tt][2] = (short)f2bf(sc * x2.z); ax1[tt][3] = (short)f2bf(sc * x2.w);
        ax1[tt][4] = (short)f2bf(sc * x3.x); ax1[tt][5] = (short)f2bf(sc * x3.y);
        ax1[tt][6] = (short)f2bf(sc * x3.z); ax1[tt][7] = (short)f2bf(sc * x3.w);
#pragma unroll
        for (int j = 0; j < 4; ++j) {
            const int g = tt * 16 + rg * 4 + j;
            bc[tt][j] = sc * (bih[g] + bhh[g]);
        }
    }

    // h-exchange: lane (n_, rg) reads s-pack sp of lanes (n_, (rg&1)*2 / +1)
    const int sp = rg >> 1;
    const int srcL0 = ((rg & 1) << 1) * 16 + n_;
    const int srcL1 = srcL0 + 16;

    const unsigned short* xTbA = xT + (size_t)chainA * 6144 + rg * 8;
    const unsigned short* xTbB = xT + (size_t)chainB * 6144 + rg * 8;

    unsigned pk0xA = 0, pk0yA = 0, pk1xA = 0, pk1yA = 0;
    unsigned pk0xB = 0, pk0yB = 0, pk1xB = 0, pk1yB = 0;
    float ccA[2][4], ccB[2][4];
#pragma unroll
    for (int s = 0; s < 2; ++s)
#pragma unroll
        for (int j = 0; j < 4; ++j) { ccA[s][j] = 0.f; ccB[s][j] = 0.f; }

    f32x4 xacA[8], xacB[8];
    bf16x8 xaA0, xbA0, xaA1, xbA1, xaA2, xbA2;
    bf16x8 xaB0, xbB0, xaB1, xbB1, xaB2, xbB2;

    FLOADU(A, xaA0, xbA0, 0) FLOADU(B, xaB0, xbB0, 0)
    FLOADU(A, xaA1, xbA1, 1) FLOADU(B, xaB1, xbB1, 1)
    PPROJ(A, xaA0, xbA0)
    PPROJ(B, xaB0, xbB0)

    for (int st = 0; st < 96; st += 3) {
        FLOADU(A, xaA2, xbA2, st + 2)
        FLOADU(B, xaB2, xbB2, st + 2)
        RSTEP(A, st)
        PPROJ(A, xaA1, xbA1)
        RSTEP(B, st)
        PPROJ(B, xaB1, xbB1)

        FLOADU(A, xaA0, xbA0, st + 3)
        FLOADU(B, xaB0, xbB0, st + 3)
        RSTEP(A, st + 1)
        PPROJ(A, xaA2, xbA2)
        RSTEP(B, st + 1)
        PPROJ(B, xaB2, xbB2)

        FLOADU(A, xaA1, xbA1, st + 4)
        FLOADU(B, xaB1, xbB1, st + 4)
        RSTEP(A, st + 2)
        PPROJ(A, xaA0, xbA0)
        RSTEP(B, st + 2)
        PPROJ(B, xaB0, xbB0)
    }
}

// ---------------------------------------------------------------------------
// Partial Gram (64x64) + channel-sum (64). 256 blocks; part in d_out scratch.
// ---------------------------------------------------------------------------
__global__ __launch_bounds__(256)
void gram_partial(const unsigned short* __restrict__ hh, float* __restrict__ part)
{
    __shared__ float xs[64][64];
    __shared__ float red[4160];
    const int tid = threadIdx.x;
    for (int e = tid; e < 4160; e += 256) red[e] = 0.0f;
    const int lane = tid & 63, wv = tid >> 6;
    const int li = lane >> 3, lj = lane & 7;
    float acc[8][8]; float macc[8];
#pragma unroll
    for (int i = 0; i < 8; ++i) {
        macc[i] = 0.f;
#pragma unroll
        for (int j = 0; j < 8; ++j) acc[i][j] = 0.f;
    }
    const size_t pix0 = (size_t)blockIdx.x * PIX_PER_BLOCK;
    for (int tile = 0; tile < PIX_PER_BLOCK / 64; ++tile) {
        __syncthreads();
        const unsigned short* src = hh + (pix0 + tile * 64) * 64;
#pragma unroll
        for (int r = 0; r < 4; ++r) {
            int idx4 = tid + 256 * r;
            ushort4 v = ((const ushort4*)src)[idx4];
            int fi = idx4 * 4; int px = fi >> 6; int c = fi & 63;
            xs[px][c] = bf2f(v.x); xs[px][c + 1] = bf2f(v.y);
            xs[px][c + 2] = bf2f(v.z); xs[px][c + 3] = bf2f(v.w);
        }
        __syncthreads();
        for (int p = wv * 16; p < wv * 16 + 16; ++p) {
            float4 ra = *(const float4*)&xs[p][8 * li];
            float4 rb = *(const float4*)&xs[p][8 * li + 4];
            float4 ca = *(const float4*)&xs[p][8 * lj];
            float4 cb = *(const float4*)&xs[p][8 * lj + 4];
            float r[8] = {ra.x, ra.y, ra.z, ra.w, rb.x, rb.y, rb.z, rb.w};
            float cl[8] = {ca.x, ca.y, ca.z, ca.w, cb.x, cb.y, cb.z, cb.w};
#pragma unroll
            for (int i = 0; i < 8; ++i) {
#pragma unroll
                for (int j = 0; j < 8; ++j) acc[i][j] = fmaf(r[i], cl[j], acc[i][j]);
            }
            if (lj == 0) {
#pragma unroll
                for (int i = 0; i < 8; ++i) macc[i] += r[i];
            }
        }
    }
    __syncthreads();
#pragma unroll
    for (int i = 0; i < 8; ++i)
#pragma unroll
        for (int j = 0; j < 8; ++j)
            atomicAdd(&red[(8 * li + i) * 64 + 8 * lj + j], acc[i][j]);
    if (lj == 0)
        for (int i = 0; i < 8; ++i) atomicAdd(&red[4096 + 8 * li + i], macc[i]);
    __syncthreads();
    for (int e = tid; e < 4160; e += 256) part[(size_t)blockIdx.x * 4160 + e] = red[e];
}

__global__ void gram_reduce(const float* __restrict__ part, float* __restrict__ M)
{
    int e = blockIdx.x * 256 + threadIdx.x;
    if (e >= 4160) return;
    double s = 0.0;
    for (int p = 0; p < GRAM_BLOCKS; ++p) s += (double)part[(size_t)p * 4160 + e];
    M[e] = (float)s;
}

// Per-output-channel affine coefficients A,B such that out = A*(w_o . u) + B.
__global__ __launch_bounds__(256)
void stats_kernel(const float* __restrict__ M, const float* __restrict__ cw,
                  const float* __restrict__ cb, const float* __restrict__ bg,
                  const float* __restrict__ bb,
                  float* __restrict__ Aout, float* __restrict__ Bout)
{
    __shared__ float Ml[4160];
    const int tid = threadIdx.x;
    for (int e = tid; e < 4160; e += 256) Ml[e] = M[e];
    __syncthreads();
    float wr[64];
#pragma unroll
    for (int c = 0; c < 64; ++c) wr[c] = bf2f(f2bf(cw[tid * 64 + c]));
    float s1 = 0.f;
#pragma unroll
    for (int c = 0; c < 64; ++c) s1 = fmaf(wr[c], Ml[4096 + c], s1);
    float s2 = 0.f;
    for (int c = 0; c < 64; ++c) {
        const float* Mr = &Ml[c * 64];
        float t = 0.f;
#pragma unroll
        for (int d = 0; d < 64; ++d) t = fmaf(wr[d], Mr[d], t);
        s2 = fmaf(wr[c], t, s2);
    }
    const double invN = 1.0 / (double)NPIX;
    double cbo = (double)cb[tid];
    double mu = (double)s1 * invN + cbo;
    double ey2 = (double)s2 * invN + 2.0 * cbo * ((double)s1 * invN) + cbo * cbo;
    double var = ey2 - mu * mu;
    double A = (double)bg[tid] / sqrt(var + 1e-5);
    Aout[tid] = (float)A;
    Bout[tid] = (float)((double)bb[tid] + A * (cbo - mu));
}

// ---------------------------------------------------------------------------
// Fused 1x1 conv + BN apply via MFMA. Block = (b,w): D[96 h][256 o].
// ---------------------------------------------------------------------------
__global__ __launch_bounds__(512, 2)
void conv_bn_kernel(const unsigned short* __restrict__ hh, const float* __restrict__ cw,
                    const float* __restrict__ Aarr, const float* __restrict__ Barr,
                    float* __restrict__ out)
{
    __shared__ alignas(16) unsigned char UsB[96 * 128];    // bf16 U, swizzled
    __shared__ alignas(16) unsigned char WtB[256 * 128];   // bf16 conv W, swizzled

    const int tid = threadIdx.x;
    const int b = blockIdx.x / 96, w = blockIdx.x % 96;

    for (int i4 = tid; i4 < 4096; i4 += 512) {
        int wrow = i4 >> 4, k4 = i4 & 15;
        float4 v = *(const float4*)(cw + (size_t)wrow * 64 + k4 * 4);
        ushort4 p; p.x = f2bf(v.x); p.y = f2bf(v.y); p.z = f2bf(v.z); p.w = f2bf(v.w);
        *(ushort4*)(WtB + wrow * 128 + ((k4 * 8) ^ ((wrow & 7) << 4))) = p;
    }
    for (int i = tid; i < 1536; i += 512) {
        int row = i >> 4, k4 = i & 15;   // row = h
        ushort4 p = *(const ushort4*)(hh + (((size_t)b * 96 + row) * 96 + w) * 64 + k4 * 4);
        *(ushort4*)(UsB + row * 128 + ((k4 * 8) ^ ((row & 7) << 4))) = p;
    }
    __syncthreads();

    const int wv = tid >> 6, lane = tid & 63;
    const int mbase = (wv >> 2) * 48, nbase = (wv & 3) * 64;
    const int lrow = lane & 15, lk = (lane >> 4) * 8;

    f32x4 acc[3][4];
#pragma unroll
    for (int m = 0; m < 3; ++m)
#pragma unroll
        for (int n = 0; n < 4; ++n)
            acc[m][n] = (f32x4){0.f, 0.f, 0.f, 0.f};

#pragma unroll
    for (int ks = 0; ks < 2; ++ks) {
        const int kb = (ks * 32 + lk) * 2;
        bf16x8 am[3], bn[4];
#pragma unroll
        for (int m = 0; m < 3; ++m) {
            int row = mbase + m * 16 + lrow;
            am[m] = *(const bf16x8*)(UsB + row * 128 + (kb ^ ((row & 7) << 4)));
        }
#pragma unroll
        for (int n = 0; n < 4; ++n) {
            int o = nbase + n * 16 + lrow;
            bn[n] = *(const bf16x8*)(WtB + o * 128 + (kb ^ ((o & 7) << 4)));
        }
#pragma unroll
        for (int m = 0; m < 3; ++m)
#pragma unroll
            for (int n = 0; n < 4; ++n)
                acc[m][n] = __builtin_amdgcn_mfma_f32_16x16x32_bf16(am[m], bn[n], acc[m][n], 0, 0, 0);
    }

    const int hbase0 = (lane >> 4) * 4;
#pragma unroll
    for (int n = 0; n < 4; ++n) {
        const int o = nbase + n * 16 + lrow;
        const float Ao = Aarr[o], Bo = Barr[o];
        float* obase = out + (((size_t)b * 256 + o) * 96 + w) * 96;
#pragma unroll
        for (int m = 0; m < 3; ++m) {
            const int h0 = mbase + m * 16 + hbase0;
            float4 res;
            res.x = fmaf(Ao, acc[m][n][0], Bo);
            res.y = fmaf(Ao, acc[m][n][1], Bo);
            res.z = fmaf(Ao, acc[m][n][2], Bo);
            res.w = fmaf(Ao, acc[m][n][3], Bo);
            *(float4*)(obase + h0) = res;
        }
    }
}

extern "C" void kernel_launch(void* const* d_in, const int* in_sizes, int n_in,
                              void* d_out, int out_size, void* d_ws, size_t ws_size,
                              hipStream_t stream)
{
    const float* x       = (const float*)d_in[0];
    const float* v_wih_f = (const float*)d_in[1];
    const float* v_whh_f = (const float*)d_in[2];
    const float* v_bih_f = (const float*)d_in[3];
    const float* v_bhh_f = (const float*)d_in[4];
    const float* v_wih_b = (const float*)d_in[5];
    const float* v_whh_b = (const float*)d_in[6];
    const float* v_bih_b = (const float*)d_in[7];
    const float* v_bhh_b = (const float*)d_in[8];
    const float* h_wih_f = (const float*)d_in[9];
    const float* h_whh_f = (const float*)d_in[10];
    const float* h_bih_f = (const float*)d_in[11];
    const float* h_bhh_f = (const float*)d_in[12];
    const float* h_wih_b = (const float*)d_in[13];
    const float* h_whh_b = (const float*)d_in[14];
    const float* h_bih_b = (const float*)d_in[15];
    const float* h_bhh_b = (const float*)d_in[16];
    const float* conv_w  = (const float*)d_in[17];
    const float* conv_b  = (const float*)d_in[18];
    const float* bn_g    = (const float*)d_in[19];
    const float* bn_b    = (const float*)d_in[20];
    float* out = (float*)d_out;

    // d_out (302 MB) doubles as scratch before conv_bn rewrites all of it:
    //   front 37.7 MB: xT (bf16 [chain=(b,w)][t=h][c]) — dead after pass 1
    //   @64 MB: gram partials (256 x 4160 f32 = 4.3 MB)
    //   tail 37.7 MB: v (bf16 [chain=(b,h)][t=w][c])  — vertical LSTM output
    const size_t v_elems = (size_t)Bn * Hn * Wn * 64;   // 18,874,368 bf16
    unsigned short* v_buf = (unsigned short*)(out + (size_t)out_size) - v_elems;
    unsigned short* xT = (unsigned short*)d_out;
    float* part = (float*)((char*)d_out + (64u << 20));

    // workspace layout
    unsigned short* hh = (unsigned short*)d_ws;                       // bf16 [B,H,W,64]
    char* wsb = (char*)d_ws;
    float* M    = (float*)(wsb + 37748736);                           // 4160 f32
    float* Aarr = M + 4160;
    float* Barr = Aarr + 256;

    // vertical pass: transpose x, then fused projection+recurrence
    transpose_x<<<3072, 256, 0, stream>>>(x, xT);
    lstm_fused<1><<<192, 64, 0, stream>>>(xT, v_wih_f, v_whh_f, v_bih_f, v_bhh_f,
                                          v_wih_b, v_whh_b, v_bih_b, v_bhh_b, v_buf);
    // horizontal pass: v is already [chain][t][c]
    lstm_fused<0><<<192, 64, 0, stream>>>(v_buf, h_wih_f, h_whh_f, h_bih_f, h_bhh_f,
                                          h_wih_b, h_whh_b, h_bih_b, h_bhh_b, hh);
    // conv + BN (affine-folded via Gram-matrix stats)
    gram_partial<<<GRAM_BLOCKS, 256, 0, stream>>>(hh, part);
    gram_reduce<<<17, 256, 0, stream>>>(part, M);
    stats_kernel<<<1, 256, 0, stream>>>(M, conv_w, conv_b, bn_g, bn_b, Aarr, Barr);
    conv_bn_kernel<<<3072, 512, 0, stream>>>(hh, conv_w, Aarr, Barr, out);
}

// Round 15
// 347.256 us; speedup vs baseline: 1.5728x; 1.5728x over previous
//
#include <hip/hip_runtime.h>
#include <stdint.h>

#define DI __device__ __forceinline__

constexpr int Bn = 32, Cc = 64, Wn = 96, Hn = 96, Ln = 32, NG = 128, OUTC = 256;
constexpr int SEQ = 96;
constexpr long long NPIX = (long long)Bn * Wn * Hn;   // 294912
constexpr int GRAM_BLOCKS = 256;
constexpr int PIX_PER_BLOCK = (int)(NPIX / GRAM_BLOCKS); // 1152

typedef __attribute__((ext_vector_type(8))) short bf16x8;
typedef __attribute__((ext_vector_type(4))) float f32x4;

constexpr float LOG2E  = 1.44269504088896340736f;
constexpr float TWOL2E = 2.88539008177792681472f;

DI float exp2_(float x) { return __builtin_amdgcn_exp2f(x); }   // v_exp_f32
DI float rcp_(float x)  { return __builtin_amdgcn_rcpf(x); }    // v_rcp_f32 (~1ulp)
DI float bf2f(unsigned short u) { return __uint_as_float(((unsigned)u) << 16); }
DI unsigned short f2bf(float f) {
    unsigned u = __float_as_uint(f);
    u += 0x7FFFu + ((u >> 16) & 1u);   // RNE
    return (unsigned short)(u >> 16);
}

union U32x4 { unsigned u[4]; bf16x8 v; };

// ---------------------------------------------------------------------------
// x transpose: [B,C,W,H] f32 -> xT[chain=(b,w)][t=h][c] bf16.
// ---------------------------------------------------------------------------
__global__ __launch_bounds__(256)
void transpose_x(const float* __restrict__ x, unsigned short* __restrict__ xT)
{
    __shared__ alignas(16) unsigned char xs[96 * 128];
    const int tid = threadIdx.x;
    const int b = blockIdx.x / 96, q = blockIdx.x % 96;
    for (int i = tid; i < 1536; i += 256) {
        int c = i / 24, h4 = i - c * 24;
        float4 v = *(const float4*)(x + (((size_t)b * 64 + c) * 96 + q) * 96 + 4 * h4);
        float vv[4] = {v.x, v.y, v.z, v.w};
#pragma unroll
        for (int j = 0; j < 4; ++j) {
            int h = 4 * h4 + j;
            *(unsigned short*)(xs + h * 128 + ((c * 2) ^ ((h & 7) << 4))) = f2bf(vv[j]);
        }
    }
    __syncthreads();
    unsigned short* ob = xT + (size_t)blockIdx.x * 6144;
    for (int i = tid; i < 768; i += 256) {
        int row = i >> 3, k8 = i & 7;
        bf16x8 p = *(const bf16x8*)(xs + row * 128 + ((k8 * 16) ^ ((row & 7) << 4)));
        *(bf16x8*)(ob + (size_t)i * 8) = p;
    }
}

// ---------------------------------------------------------------------------
// FUSED BiLSTM (R15 = R12's proven 1-unit structure + pointer-increment
// stores). R13 evidence: 2-unit interleave regressed 1.77x AGAIN even with
// lean activations -> per-unit issue is ~1700+cyc/step (transcendental issue
// + VALU pack/addr), not stall-dominated. Keep 1 unit/wave, 384 blocks.
// Per step: P(t+1) = 16 h-independent MFMAs (Wih@x, bias C-in) -> xac bank;
// R(t) = 8 shfl (h) -> 8 dependent MFMA -> exp2-domain activations -> store
// via running pointer (odelta), removing per-step 64-bit address math.
// Weights pre-scaled by log2e (g-gate tiles by 2*log2e).
// ---------------------------------------------------------------------------
#define FLOAD(XA, XB, STI)                                                     \
    if ((STI) < 96) {                                                          \
        const int tl_ = dir ? 95 - (STI) : (STI);                              \
        XA = *(const bf16x8*)(xTb + (size_t)tl_ * 64);                         \
        XB = *(const bf16x8*)(xTb + (size_t)tl_ * 64 + 32);                    \
    }

#define PPROJ(XA, XB)                                                          \
    _Pragma("unroll")                                                          \
    for (int tt = 0; tt < 8; ++tt) {                                           \
        f32x4 tp_ = __builtin_amdgcn_mfma_f32_16x16x32_bf16(ax0[tt], XA, bc[tt], 0, 0, 0); \
        xac[tt] = __builtin_amdgcn_mfma_f32_16x16x32_bf16(ax1[tt], XB, tp_, 0, 0, 0);      \
    }

#define RSTEP(STI)                                                             \
    {                                                                          \
        U32x4 hu;                                                              \
        {                                                                      \
            int a0 = __shfl((int)pk0x, srcL0), a1 = __shfl((int)pk0y, srcL0);  \
            int a2 = __shfl((int)pk0x, srcL1), a3 = __shfl((int)pk0y, srcL1);  \
            int b0 = __shfl((int)pk1x, srcL0), b1 = __shfl((int)pk1y, srcL0);  \
            int b2 = __shfl((int)pk1x, srcL1), b3 = __shfl((int)pk1y, srcL1);  \
            hu.u[0] = sp ? (unsigned)b0 : (unsigned)a0;                        \
            hu.u[1] = sp ? (unsigned)b1 : (unsigned)a1;                        \
            hu.u[2] = sp ? (unsigned)b2 : (unsigned)a2;                        \
            hu.u[3] = sp ? (unsigned)b3 : (unsigned)a3;                        \
        }                                                                      \
        f32x4 ac_[8];                                                          \
        _Pragma("unroll")                                                      \
        for (int tt = 0; tt < 8; ++tt)                                         \
            ac_[tt] = __builtin_amdgcn_mfma_f32_16x16x32_bf16(ah[tt], hu.v, xac[tt], 0, 0, 0); \
        _Pragma("unroll")                                                      \
        for (int s = 0; s < 2; ++s) {                                          \
            unsigned short hs[4];                                              \
            _Pragma("unroll")                                                  \
            for (int j = 0; j < 4; ++j) {                                      \
                const float iv = rcp_(1.f + exp2_(-ac_[0 + s][j]));            \
                const float fv = rcp_(1.f + exp2_(-ac_[2 + s][j]));            \
                const float gr = rcp_(1.f + exp2_(-ac_[4 + s][j]));            \
                const float gv = fmaf(2.f, gr, -1.f);                          \
                const float ov = rcp_(1.f + exp2_(-ac_[6 + s][j]));            \
                cc[s][j] = fmaf(fv, cc[s][j], iv * gv);                        \
                const float r_ = rcp_(exp2_(cc[s][j] * TWOL2E) + 1.f);         \
                const float t2 = -2.f * ov;                                    \
                hs[j] = f2bf(fmaf(t2, r_, ov));                                \
            }                                                                  \
            const unsigned dlo = ((unsigned)hs[1] << 16) | hs[0];              \
            const unsigned dhi = ((unsigned)hs[3] << 16) | hs[2];              \
            if (s == 0) { pk0x = dlo; pk0y = dhi; } else { pk1x = dlo; pk1y = dhi; } \
            ushort4 hp; hp.x = hs[0]; hp.y = hs[1]; hp.z = hs[2]; hp.w = hs[3];\
            *(ushort4*)(optr + s * 16) = hp;                                   \
        }                                                                      \
        optr += odelta;                                                        \
    }

template<int VERT>
__global__ __launch_bounds__(64, 1)
void lstm_fused(const unsigned short* __restrict__ xT,
                const float* __restrict__ wih_f, const float* __restrict__ whh_f,
                const float* __restrict__ bih_f, const float* __restrict__ bhh_f,
                const float* __restrict__ wih_b, const float* __restrict__ whh_b,
                const float* __restrict__ bih_b, const float* __restrict__ bhh_b,
                unsigned short* __restrict__ outU)
{
    const int lane = threadIdx.x;
    const int dir = blockIdx.x & 1, group = blockIdx.x >> 1;   // group in [0,192)
    const int n_ = lane & 15, rg = lane >> 4;
    const int chain = group * 16 + n_;
    const int b = group / 6;
    const int q = (group % 6) * 16 + n_;

    const float* wih = dir ? wih_b : wih_f;
    const float* whh = dir ? whh_b : whh_f;
    const float* bih = dir ? bih_b : bih_f;
    const float* bhh = dir ? bhh_b : bhh_f;

    // Weight fragments, pre-scaled into exp2 domain (g-gate tiles 4,5 by
    // 2*log2e). Mapping refcheck'd R9-R13. lane (n_, rg): row = tt*16+n_,
    // k = rg*8..+8.
    bf16x8 ah[8], ax0[8], ax1[8];
    f32x4 bc[8];
#pragma unroll
    for (int tt = 0; tt < 8; ++tt) {
        const float sc = (tt == 4 || tt == 5) ? TWOL2E : LOG2E;
        const float* sh = whh + (size_t)(tt * 16 + n_) * 32 + rg * 8;
        const float* sx = wih + (size_t)(tt * 16 + n_) * 64 + rg * 8;
        float4 h0 = *(const float4*)sh, h1 = *(const float4*)(sh + 4);
        float4 x0 = *(const float4*)sx, x1 = *(const float4*)(sx + 4);
        float4 x2 = *(const float4*)(sx + 32), x3 = *(const float4*)(sx + 36);
        ah[tt][0] = (short)f2bf(sc * h0.x); ah[tt][1] = (short)f2bf(sc * h0.y);
        ah[tt][2] = (short)f2bf(sc * h0.z); ah[tt][3] = (short)f2bf(sc * h0.w);
        ah[tt][4] = (short)f2bf(sc * h1.x); ah[tt][5] = (short)f2bf(sc * h1.y);
        ah[tt][6] = (short)f2bf(sc * h1.z); ah[tt][7] = (short)f2bf(sc * h1.w);
        ax0[tt][0] = (short)f2bf(sc * x0.x); ax0[tt][1] = (short)f2bf(sc * x0.y);
        ax0[tt][2] = (short)f2bf(sc * x0.z); ax0[tt][3] = (short)f2bf(sc * x0.w);
        ax0[tt][4] = (short)f2bf(sc * x1.x); ax0[tt][5] = (short)f2bf(sc * x1.y);
        ax0[tt][6] = (short)f2bf(sc * x1.z); ax0[tt][7] = (short)f2bf(sc * x1.w);
        ax1[tt][0] = (short)f2bf(sc * x2.x); ax1[tt][1] = (short)f2bf(sc * x2.y);
        ax1[tt][2] = (short)f2bf(sc * x2.z); ax1[tt][3] = (short)f2bf(sc * x2.w);
        ax1[tt][4] = (short)f2bf(sc * x3.x); ax1[tt][5] = (short)f2bf(sc * x3.y);
        ax1[tt][6] = (short)f2bf(sc * x3.z); ax1[tt][7] = (short)f2bf(sc * x3.w);
#pragma unroll
        for (int j = 0; j < 4; ++j) {
            const int g = tt * 16 + rg * 4 + j;
            bc[tt][j] = sc * (bih[g] + bhh[g]);
        }
    }

    // h-exchange: lane (n_, rg) reads s-pack sp of lanes (n_, (rg&1)*2 / +1)
    const int sp = rg >> 1;
    const int srcL0 = ((rg & 1) << 1) * 16 + n_;
    const int srcL1 = srcL0 + 16;

    const unsigned short* xTb = xT + (size_t)chain * 6144 + rg * 8;

    // running output pointer (replaces per-step 64-bit address math)
    const int t0 = dir ? 95 : 0;
    const size_t o0 = VERT ? ((((size_t)b * 96 + t0) * 96 + q) * 64)
                           : ((((size_t)b * 96 + q) * 96 + t0) * 64);
    unsigned short* optr = outU + o0 + dir * 32 + rg * 4;
    const ptrdiff_t odelta = (ptrdiff_t)(dir ? -1 : 1) * (VERT ? 6144 : 64);

    unsigned pk0x = 0, pk0y = 0, pk1x = 0, pk1y = 0;   // h packs (s=0 / s=1)
    float cc[2][4];
#pragma unroll
    for (int s = 0; s < 2; ++s)
#pragma unroll
        for (int j = 0; j < 4; ++j) cc[s][j] = 0.f;

    f32x4 xac[8];
    bf16x8 xa0, xb0, xa1, xb1, xa2, xb2;
    FLOAD(xa0, xb0, 0)
    FLOAD(xa1, xb1, 1)
    PPROJ(xa0, xb0)

    for (int st = 0; st < 96; st += 3) {
        FLOAD(xa2, xb2, st + 2)
        RSTEP(st)
        PPROJ(xa1, xb1)
        FLOAD(xa0, xb0, st + 3)
        RSTEP(st + 1)
        PPROJ(xa2, xb2)
        FLOAD(xa1, xb1, st + 4)
        RSTEP(st + 2)
        PPROJ(xa0, xb0)
    }
}

// ---------------------------------------------------------------------------
// Partial Gram (64x64) + channel-sum via MFMA (R14/R15 rewrite). Gram = X^T X
// is matmul-shaped with K = NPIX (Guideline 10); the old 8x8 VALU register
// tile ran ~65us vs ~16us VALU floor. Symmetry => A and B fragments read the
// SAME transposed LDS image XsT[c][p] (row stride 144B: 16B-aligned, ~2-way
// banks). Staging transposes hh (coalesced 8B loads -> 4 scalar ds_write_b16)
// and accumulates channel sums in registers. Double-buffered, 1 barrier/tile.
// Wave w computes m-tile w x all 4 n-tiles; 8 MFMAs per 64-pixel tile.
// ---------------------------------------------------------------------------
__global__ __launch_bounds__(256, 2)
void gram_partial(const unsigned short* __restrict__ hh, float* __restrict__ part)
{
    __shared__ alignas(16) unsigned char xsT[2][64 * 144];  // bf16 [c][p], 144B rows
    __shared__ float sumb[16][64];

    const int tid = threadIdx.x;
    const int wv = tid >> 6, lane = tid & 63;
    const int lrow = lane & 15, lkg = lane >> 4;
    const int cq = tid & 15, pr = tid >> 4;

    float csum[4] = {0.f, 0.f, 0.f, 0.f};
    f32x4 acc[4];
#pragma unroll
    for (int n = 0; n < 4; ++n) acc[n] = (f32x4){0.f, 0.f, 0.f, 0.f};

    const size_t pix0 = (size_t)blockIdx.x * PIX_PER_BLOCK;

    for (int tile = 0; tile < PIX_PER_BLOCK / 64; ++tile) {
        unsigned char* Xb = xsT[tile & 1];
        // stage: thread (pr, cq) covers pixels pr, pr+16, pr+32, pr+48; chans cq*4..+3
#pragma unroll
        for (int r = 0; r < 4; ++r) {
            const int p = pr + r * 16;
            ushort4 v = *(const ushort4*)(hh + (pix0 + (size_t)tile * 64 + p) * 64 + cq * 4);
            csum[0] += bf2f(v.x); csum[1] += bf2f(v.y);
            csum[2] += bf2f(v.z); csum[3] += bf2f(v.w);
            *(unsigned short*)(Xb + (cq * 4 + 0) * 144 + p * 2) = v.x;
            *(unsigned short*)(Xb + (cq * 4 + 1) * 144 + p * 2) = v.y;
            *(unsigned short*)(Xb + (cq * 4 + 2) * 144 + p * 2) = v.z;
            *(unsigned short*)(Xb + (cq * 4 + 3) * 144 + p * 2) = v.w;
        }
        __syncthreads();
        // MFMA: A[m=c][k=p], B[k=p][n=c'] both = XsT rows (Gram symmetry)
#pragma unroll
        for (int kc = 0; kc < 2; ++kc) {
            const int kb = (kc * 32 + lkg * 8) * 2;
            bf16x8 af = *(const bf16x8*)(Xb + (wv * 16 + lrow) * 144 + kb);
#pragma unroll
            for (int n = 0; n < 4; ++n) {
                bf16x8 bf_ = *(const bf16x8*)(Xb + (n * 16 + lrow) * 144 + kb);
                acc[n] = __builtin_amdgcn_mfma_f32_16x16x32_bf16(af, bf_, acc[n], 0, 0, 0);
            }
        }
        // next stage writes the other buffer; the tile+1 barrier orders this
        // MFMA's reads vs the tile+2 overwrite.
    }

    // channel sums: reduce 16 partial rows
    *(float4*)&sumb[pr][cq * 4] = (float4){csum[0], csum[1], csum[2], csum[3]};
    __syncthreads();
    float* pb = part + (size_t)blockIdx.x * 4160;
    if (tid < 64) {
        float s = 0.f;
#pragma unroll
        for (int r = 0; r < 16; ++r) s += sumb[r][tid];
        pb[4096 + tid] = s;
    }
    // gram: D col = n*16 + (lane&15), row = wv*16 + (lane>>4)*4 + r
#pragma unroll
    for (int n = 0; n < 4; ++n)
#pragma unroll
        for (int r = 0; r < 4; ++r)
            pb[(wv * 16 + lkg * 4 + r) * 64 + n * 16 + lrow] = acc[n][r];
}

__global__ void gram_reduce(const float* __restrict__ part, float* __restrict__ M)
{
    int e = blockIdx.x * 256 + threadIdx.x;
    if (e >= 4160) return;
    double s = 0.0;
    for (int p = 0; p < GRAM_BLOCKS; ++p) s += (double)part[(size_t)p * 4160 + e];
    M[e] = (float)s;
}

// Per-output-channel affine coefficients A,B such that out = A*(w_o . u) + B.
__global__ __launch_bounds__(256)
void stats_kernel(const float* __restrict__ M, const float* __restrict__ cw,
                  const float* __restrict__ cb, const float* __restrict__ bg,
                  const float* __restrict__ bb,
                  float* __restrict__ Aout, float* __restrict__ Bout)
{
    __shared__ float Ml[4160];
    const int tid = threadIdx.x;
    for (int e = tid; e < 4160; e += 256) Ml[e] = M[e];
    __syncthreads();
    float wr[64];
#pragma unroll
    for (int c = 0; c < 64; ++c) wr[c] = bf2f(f2bf(cw[tid * 64 + c]));
    float s1 = 0.f;
#pragma unroll
    for (int c = 0; c < 64; ++c) s1 = fmaf(wr[c], Ml[4096 + c], s1);
    float s2 = 0.f;
    for (int c = 0; c < 64; ++c) {
        const float* Mr = &Ml[c * 64];
        float t = 0.f;
#pragma unroll
        for (int d = 0; d < 64; ++d) t = fmaf(wr[d], Mr[d], t);
        s2 = fmaf(wr[c], t, s2);
    }
    const double invN = 1.0 / (double)NPIX;
    double cbo = (double)cb[tid];
    double mu = (double)s1 * invN + cbo;
    double ey2 = (double)s2 * invN + 2.0 * cbo * ((double)s1 * invN) + cbo * cbo;
    double var = ey2 - mu * mu;
    double A = (double)bg[tid] / sqrt(var + 1e-5);
    Aout[tid] = (float)A;
    Bout[tid] = (float)((double)bb[tid] + A * (cbo - mu));
}

// ---------------------------------------------------------------------------
// Fused 1x1 conv + BN apply via MFMA. Block = (b,w): D[96 h][256 o].
// R15: nontemporal stores via ext-vector f32x4 (302MB streaming output,
// never re-read; HIP float4 is a class type the builtin rejects — R14).
// ---------------------------------------------------------------------------
__global__ __launch_bounds__(512, 2)
void conv_bn_kernel(const unsigned short* __restrict__ hh, const float* __restrict__ cw,
                    const float* __restrict__ Aarr, const float* __restrict__ Barr,
                    float* __restrict__ out)
{
    __shared__ alignas(16) unsigned char UsB[96 * 128];    // bf16 U, swizzled
    __shared__ alignas(16) unsigned char WtB[256 * 128];   // bf16 conv W, swizzled

    const int tid = threadIdx.x;
    const int b = blockIdx.x / 96, w = blockIdx.x % 96;

    for (int i4 = tid; i4 < 4096; i4 += 512) {
        int wrow = i4 >> 4, k4 = i4 & 15;
        float4 v = *(const float4*)(cw + (size_t)wrow * 64 + k4 * 4);
        ushort4 p; p.x = f2bf(v.x); p.y = f2bf(v.y); p.z = f2bf(v.z); p.w = f2bf(v.w);
        *(ushort4*)(WtB + wrow * 128 + ((k4 * 8) ^ ((wrow & 7) << 4))) = p;
    }
    for (int i = tid; i < 1536; i += 512) {
        int row = i >> 4, k4 = i & 15;   // row = h
        ushort4 p = *(const ushort4*)(hh + (((size_t)b * 96 + row) * 96 + w) * 64 + k4 * 4);
        *(ushort4*)(UsB + row * 128 + ((k4 * 8) ^ ((row & 7) << 4))) = p;
    }
    __syncthreads();

    const int wv = tid >> 6, lane = tid & 63;
    const int mbase = (wv >> 2) * 48, nbase = (wv & 3) * 64;
    const int lrow = lane & 15, lk = (lane >> 4) * 8;

    f32x4 acc[3][4];
#pragma unroll
    for (int m = 0; m < 3; ++m)
#pragma unroll
        for (int n = 0; n < 4; ++n)
            acc[m][n] = (f32x4){0.f, 0.f, 0.f, 0.f};

#pragma unroll
    for (int ks = 0; ks < 2; ++ks) {
        const int kb = (ks * 32 + lk) * 2;
        bf16x8 am[3], bn[4];
#pragma unroll
        for (int m = 0; m < 3; ++m) {
            int row = mbase + m * 16 + lrow;
            am[m] = *(const bf16x8*)(UsB + row * 128 + (kb ^ ((row & 7) << 4)));
        }
#pragma unroll
        for (int n = 0; n < 4; ++n) {
            int o = nbase + n * 16 + lrow;
            bn[n] = *(const bf16x8*)(WtB + o * 128 + (kb ^ ((o & 7) << 4)));
        }
#pragma unroll
        for (int m = 0; m < 3; ++m)
#pragma unroll
            for (int n = 0; n < 4; ++n)
                acc[m][n] = __builtin_amdgcn_mfma_f32_16x16x32_bf16(am[m], bn[n], acc[m][n], 0, 0, 0);
    }

    const int hbase0 = (lane >> 4) * 4;
#pragma unroll
    for (int n = 0; n < 4; ++n) {
        const int o = nbase + n * 16 + lrow;
        const float Ao = Aarr[o], Bo = Barr[o];
        float* obase = out + (((size_t)b * 256 + o) * 96 + w) * 96;
#pragma unroll
        for (int m = 0; m < 3; ++m) {
            const int h0 = mbase + m * 16 + hbase0;
            f32x4 res;
            res[0] = fmaf(Ao, acc[m][n][0], Bo);
            res[1] = fmaf(Ao, acc[m][n][1], Bo);
            res[2] = fmaf(Ao, acc[m][n][2], Bo);
            res[3] = fmaf(Ao, acc[m][n][3], Bo);
            __builtin_nontemporal_store(res, (f32x4*)(obase + h0));
        }
    }
}

extern "C" void kernel_launch(void* const* d_in, const int* in_sizes, int n_in,
                              void* d_out, int out_size, void* d_ws, size_t ws_size,
                              hipStream_t stream)
{
    const float* x       = (const float*)d_in[0];
    const float* v_wih_f = (const float*)d_in[1];
    const float* v_whh_f = (const float*)d_in[2];
    const float* v_bih_f = (const float*)d_in[3];
    const float* v_bhh_f = (const float*)d_in[4];
    const float* v_wih_b = (const float*)d_in[5];
    const float* v_whh_b = (const float*)d_in[6];
    const float* v_bih_b = (const float*)d_in[7];
    const float* v_bhh_b = (const float*)d_in[8];
    const float* h_wih_f = (const float*)d_in[9];
    const float* h_whh_f = (const float*)d_in[10];
    const float* h_bih_f = (const float*)d_in[11];
    const float* h_bhh_f = (const float*)d_in[12];
    const float* h_wih_b = (const float*)d_in[13];
    const float* h_whh_b = (const float*)d_in[14];
    const float* h_bih_b = (const float*)d_in[15];
    const float* h_bhh_b = (const float*)d_in[16];
    const float* conv_w  = (const float*)d_in[17];
    const float* conv_b  = (const float*)d_in[18];
    const float* bn_g    = (const float*)d_in[19];
    const float* bn_b    = (const float*)d_in[20];
    float* out = (float*)d_out;

    // d_out (302 MB) doubles as scratch before conv_bn rewrites all of it:
    //   front 37.7 MB: xT (bf16 [chain=(b,w)][t=h][c]) — dead after pass 1
    //   @64 MB: gram partials (256 x 4160 f32 = 4.3 MB)
    //   tail 37.7 MB: v (bf16 [chain=(b,h)][t=w][c])  — vertical LSTM output
    const size_t v_elems = (size_t)Bn * Hn * Wn * 64;   // 18,874,368 bf16
    unsigned short* v_buf = (unsigned short*)(out + (size_t)out_size) - v_elems;
    unsigned short* xT = (unsigned short*)d_out;
    float* part = (float*)((char*)d_out + (64u << 20));

    // workspace layout
    unsigned short* hh = (unsigned short*)d_ws;                       // bf16 [B,H,W,64]
    char* wsb = (char*)d_ws;
    float* M    = (float*)(wsb + 37748736);                           // 4160 f32
    float* Aarr = M + 4160;
    float* Barr = Aarr + 256;

    // vertical pass: transpose x, then fused projection+recurrence
    transpose_x<<<3072, 256, 0, stream>>>(x, xT);
    lstm_fused<1><<<384, 64, 0, stream>>>(xT, v_wih_f, v_whh_f, v_bih_f, v_bhh_f,
                                          v_wih_b, v_whh_b, v_bih_b, v_bhh_b, v_buf);
    // horizontal pass: v is already [chain][t][c]
    lstm_fused<0><<<384, 64, 0, stream>>>(v_buf, h_wih_f, h_whh_f, h_bih_f, h_bhh_f,
                                          h_wih_b, h_whh_b, h_bih_b, h_bhh_b, hh);
    // conv + BN (affine-folded via Gram-matrix stats)
    gram_partial<<<GRAM_BLOCKS, 256, 0, stream>>>(hh, part);
    gram_reduce<<<17, 256, 0, stream>>>(part, M);
    stats_kernel<<<1, 256, 0, stream>>>(M, conv_w, conv_b, bn_g, bn_b, Aarr, Barr);
    conv_bn_kernel<<<3072, 512, 0, stream>>>(hh, conv_w, Aarr, Barr, out);
}

// Round 16
// 339.186 us; speedup vs baseline: 1.6102x; 1.0238x over previous
//
#include <hip/hip_runtime.h>
#include <stdint.h>

#define DI __device__ __forceinline__

constexpr int Bn = 32, Cc = 64, Wn = 96, Hn = 96, Ln = 32, NG = 128, OUTC = 256;
constexpr int SEQ = 96;
constexpr long long NPIX = (long long)Bn * Wn * Hn;   // 294912
constexpr int GRAM_BLOCKS = 256;
constexpr int PIX_PER_BLOCK = (int)(NPIX / GRAM_BLOCKS); // 1152

typedef __attribute__((ext_vector_type(8))) short bf16x8;
typedef __attribute__((ext_vector_type(4))) float f32x4;

constexpr float LOG2E  = 1.44269504088896340736f;
constexpr float TWOL2E = 2.88539008177792681472f;

DI float exp2_(float x) { return __builtin_amdgcn_exp2f(x); }   // v_exp_f32
DI float rcp_(float x)  { return __builtin_amdgcn_rcpf(x); }    // v_rcp_f32 (~1ulp)
DI float bf2f(unsigned short u) { return __uint_as_float(((unsigned)u) << 16); }
DI unsigned short f2bf(float f) {
    unsigned u = __float_as_uint(f);
    u += 0x7FFFu + ((u >> 16) & 1u);   // RNE
    return (unsigned short)(u >> 16);
}

// ---------------------------------------------------------------------------
// x transpose: [B,C,W,H] f32 -> xT[chain=(b,w)][t=h][c] bf16.
// ---------------------------------------------------------------------------
__global__ __launch_bounds__(256)
void transpose_x(const float* __restrict__ x, unsigned short* __restrict__ xT)
{
    __shared__ alignas(16) unsigned char xs[96 * 128];
    const int tid = threadIdx.x;
    const int b = blockIdx.x / 96, q = blockIdx.x % 96;
    for (int i = tid; i < 1536; i += 256) {
        int c = i / 24, h4 = i - c * 24;
        float4 v = *(const float4*)(x + (((size_t)b * 64 + c) * 96 + q) * 96 + 4 * h4);
        float vv[4] = {v.x, v.y, v.z, v.w};
#pragma unroll
        for (int j = 0; j < 4; ++j) {
            int h = 4 * h4 + j;
            *(unsigned short*)(xs + h * 128 + ((c * 2) ^ ((h & 7) << 4))) = f2bf(vv[j]);
        }
    }
    __syncthreads();
    unsigned short* ob = xT + (size_t)blockIdx.x * 6144;
    for (int i = tid; i < 768; i += 256) {
        int row = i >> 3, k8 = i & 7;
        bf16x8 p = *(const bf16x8*)(xs + row * 128 + ((k8 * 16) ^ ((row & 7) << 4)));
        *(bf16x8*)(ob + (size_t)i * 8) = p;
    }
}

// ---------------------------------------------------------------------------
// FUSED BiLSTM (R16): 2 WAVES PER UNIT, split by s-group. R15 evidence:
// lstm ~85us/pass; per-chip transcendental throughput is the bottleneck
// (189M trans ops; only 384/1024 SIMDs active -> each wave serially issues
// ~7680 wave-trans-ops ~ 50us/pass of pure trans issue). R13: adding work
// per wave scales ~1.77x (issue-bound) -> the fix is MORE WAVES.
// Gate tiles are s-indexed: wave wv owns tiles {wv,2+wv,4+wv,6+wv} = cells
// wv*16..+15 (self-contained cell update: 12 MFMA, 40 trans/lane/step).
// Cross-wave h via double-buffered LDS h[chain][32cells] (80B stride, 2-way
// banks = free; replaces the 8-shfl exchange), ONE barrier/step.
// 768 waves -> 75% SIMD coverage, ~2x chip trans throughput.
// ---------------------------------------------------------------------------
#define FLOAD(XA, XB, STI)                                                     \
    if ((STI) < 96) {                                                          \
        const int tl_ = dir ? 95 - (STI) : (STI);                              \
        XA = *(const bf16x8*)(xTb + (size_t)tl_ * 64);                         \
        XB = *(const bf16x8*)(xTb + (size_t)tl_ * 64 + 32);                    \
    }

#define PPROJ(XA, XB)                                                          \
    _Pragma("unroll")                                                          \
    for (int g_ = 0; g_ < 4; ++g_) {                                           \
        f32x4 tp_ = __builtin_amdgcn_mfma_f32_16x16x32_bf16(ax0[g_], XA, bc[g_], 0, 0, 0); \
        xac[g_] = __builtin_amdgcn_mfma_f32_16x16x32_bf16(ax1[g_], XB, tp_, 0, 0, 0);      \
    }

#define RSTEP(STI)                                                             \
    {                                                                          \
        const bf16x8 hu = *(const bf16x8*)(hcur + n_ * 80 + rg * 16);          \
        f32x4 ac_[4];                                                          \
        _Pragma("unroll")                                                      \
        for (int g_ = 0; g_ < 4; ++g_)                                         \
            ac_[g_] = __builtin_amdgcn_mfma_f32_16x16x32_bf16(ah[g_], hu, xac[g_], 0, 0, 0); \
        unsigned short hs[4];                                                  \
        _Pragma("unroll")                                                      \
        for (int j = 0; j < 4; ++j) {                                          \
            const float iv = rcp_(1.f + exp2_(-ac_[0][j]));                    \
            const float fv = rcp_(1.f + exp2_(-ac_[1][j]));                    \
            const float gr = rcp_(1.f + exp2_(-ac_[2][j]));                    \
            const float gv = fmaf(2.f, gr, -1.f);                              \
            const float ov = rcp_(1.f + exp2_(-ac_[3][j]));                    \
            cc[j] = fmaf(fv, cc[j], iv * gv);                                  \
            const float r_ = rcp_(exp2_(cc[j] * TWOL2E) + 1.f);                \
            const float t2 = -2.f * ov;                                        \
            hs[j] = f2bf(fmaf(t2, r_, ov));                                    \
        }                                                                      \
        ushort4 hp; hp.x = hs[0]; hp.y = hs[1]; hp.z = hs[2]; hp.w = hs[3];    \
        *(ushort4*)(hnxt + n_ * 80 + wv * 32 + rg * 8) = hp;                   \
        *(ushort4*)optr = hp;                                                  \
        optr += odelta;                                                        \
        __syncthreads();                                                       \
        { unsigned char* t_ = hcur; hcur = hnxt; hnxt = t_; }                  \
    }

template<int VERT>
__global__ __launch_bounds__(128, 1)
void lstm_fused(const unsigned short* __restrict__ xT,
                const float* __restrict__ wih_f, const float* __restrict__ whh_f,
                const float* __restrict__ bih_f, const float* __restrict__ bhh_f,
                const float* __restrict__ wih_b, const float* __restrict__ whh_b,
                const float* __restrict__ bih_b, const float* __restrict__ bhh_b,
                unsigned short* __restrict__ outU)
{
    __shared__ alignas(16) unsigned char hbuf[2][16 * 80];  // h[chain][32cells] bf16, 80B stride

    const int tid = threadIdx.x;
    const int wv = tid >> 6, lane = tid & 63;
    const int dir = blockIdx.x & 1, group = blockIdx.x >> 1;   // group in [0,192)
    const int n_ = lane & 15, rg = lane >> 4;
    const int chain = group * 16 + n_;
    const int b = group / 6;
    const int q = (group % 6) * 16 + n_;

    const float* wih = dir ? wih_b : wih_f;
    const float* whh = dir ? whh_b : whh_f;
    const float* bih = dir ? bih_b : bih_f;
    const float* bhh = dir ? bhh_b : bhh_f;

    // Wave wv owns gate tiles tt = 2*g_ + wv (g_ = i,f,g,o), i.e. cells
    // wv*16 .. wv*16+15. Weights pre-scaled into exp2 domain (g-gate by
    // 2*log2e). Fragment mapping refcheck'd R9-R15: lane (n_, rg):
    // row = tt*16 + n_, k = rg*8..+8.
    bf16x8 ah[4], ax0[4], ax1[4];
    f32x4 bc[4];
#pragma unroll
    for (int g_ = 0; g_ < 4; ++g_) {
        const int tt = 2 * g_ + wv;
        const float sc = (g_ == 2) ? TWOL2E : LOG2E;
        const float* sh = whh + (size_t)(tt * 16 + n_) * 32 + rg * 8;
        const float* sx = wih + (size_t)(tt * 16 + n_) * 64 + rg * 8;
        float4 h0 = *(const float4*)sh, h1 = *(const float4*)(sh + 4);
        float4 x0 = *(const float4*)sx, x1 = *(const float4*)(sx + 4);
        float4 x2 = *(const float4*)(sx + 32), x3 = *(const float4*)(sx + 36);
        ah[g_][0] = (short)f2bf(sc * h0.x); ah[g_][1] = (short)f2bf(sc * h0.y);
        ah[g_][2] = (short)f2bf(sc * h0.z); ah[g_][3] = (short)f2bf(sc * h0.w);
        ah[g_][4] = (short)f2bf(sc * h1.x); ah[g_][5] = (short)f2bf(sc * h1.y);
        ah[g_][6] = (short)f2bf(sc * h1.z); ah[g_][7] = (short)f2bf(sc * h1.w);
        ax0[g_][0] = (short)f2bf(sc * x0.x); ax0[g_][1] = (short)f2bf(sc * x0.y);
        ax0[g_][2] = (short)f2bf(sc * x0.z); ax0[g_][3] = (short)f2bf(sc * x0.w);
        ax0[g_][4] = (short)f2bf(sc * x1.x); ax0[g_][5] = (short)f2bf(sc * x1.y);
        ax0[g_][6] = (short)f2bf(sc * x1.z); ax0[g_][7] = (short)f2bf(sc * x1.w);
        ax1[g_][0] = (short)f2bf(sc * x2.x); ax1[g_][1] = (short)f2bf(sc * x2.y);
        ax1[g_][2] = (short)f2bf(sc * x2.z); ax1[g_][3] = (short)f2bf(sc * x2.w);
        ax1[g_][4] = (short)f2bf(sc * x3.x); ax1[g_][5] = (short)f2bf(sc * x3.y);
        ax1[g_][6] = (short)f2bf(sc * x3.z); ax1[g_][7] = (short)f2bf(sc * x3.w);
#pragma unroll
        for (int j = 0; j < 4; ++j) {
            const int g = tt * 16 + rg * 4 + j;
            bc[g_][j] = sc * (bih[g] + bhh[g]);
        }
    }

    const unsigned short* xTb = xT + (size_t)chain * 6144 + rg * 8;

    // running output pointer; this wave stores its s-group's pack only
    const int t0 = dir ? 95 : 0;
    const size_t o0 = VERT ? ((((size_t)b * 96 + t0) * 96 + q) * 64)
                           : ((((size_t)b * 96 + q) * 96 + t0) * 64);
    unsigned short* optr = outU + o0 + dir * 32 + wv * 16 + rg * 4;
    const ptrdiff_t odelta = (ptrdiff_t)(dir ? -1 : 1) * (VERT ? 6144 : 64);

    // zero initial h (buffer 0 only); both waves participate
    for (int i = tid; i < 320; i += 128) ((unsigned*)hbuf[0])[i] = 0u;

    unsigned char* hcur = hbuf[0];
    unsigned char* hnxt = hbuf[1];

    float cc[4] = {0.f, 0.f, 0.f, 0.f};
    f32x4 xac[4];
    bf16x8 xa0, xb0, xa1, xb1, xa2, xb2;
    FLOAD(xa0, xb0, 0)
    FLOAD(xa1, xb1, 1)
    PPROJ(xa0, xb0)
    __syncthreads();

    for (int st = 0; st < 96; st += 3) {
        FLOAD(xa2, xb2, st + 2)
        RSTEP(st)
        PPROJ(xa1, xb1)
        FLOAD(xa0, xb0, st + 3)
        RSTEP(st + 1)
        PPROJ(xa2, xb2)
        FLOAD(xa1, xb1, st + 4)
        RSTEP(st + 2)
        PPROJ(xa0, xb0)
    }
}

// ---------------------------------------------------------------------------
// Partial Gram (64x64) + channel-sum via MFMA (R14/R15, passed). Symmetry =>
// A and B fragments read the SAME transposed LDS image XsT[c][p] (144B rows).
// ---------------------------------------------------------------------------
__global__ __launch_bounds__(256, 2)
void gram_partial(const unsigned short* __restrict__ hh, float* __restrict__ part)
{
    __shared__ alignas(16) unsigned char xsT[2][64 * 144];  // bf16 [c][p], 144B rows
    __shared__ float sumb[16][64];

    const int tid = threadIdx.x;
    const int wv = tid >> 6, lane = tid & 63;
    const int lrow = lane & 15, lkg = lane >> 4;
    const int cq = tid & 15, pr = tid >> 4;

    float csum[4] = {0.f, 0.f, 0.f, 0.f};
    f32x4 acc[4];
#pragma unroll
    for (int n = 0; n < 4; ++n) acc[n] = (f32x4){0.f, 0.f, 0.f, 0.f};

    const size_t pix0 = (size_t)blockIdx.x * PIX_PER_BLOCK;

    for (int tile = 0; tile < PIX_PER_BLOCK / 64; ++tile) {
        unsigned char* Xb = xsT[tile & 1];
#pragma unroll
        for (int r = 0; r < 4; ++r) {
            const int p = pr + r * 16;
            ushort4 v = *(const ushort4*)(hh + (pix0 + (size_t)tile * 64 + p) * 64 + cq * 4);
            csum[0] += bf2f(v.x); csum[1] += bf2f(v.y);
            csum[2] += bf2f(v.z); csum[3] += bf2f(v.w);
            *(unsigned short*)(Xb + (cq * 4 + 0) * 144 + p * 2) = v.x;
            *(unsigned short*)(Xb + (cq * 4 + 1) * 144 + p * 2) = v.y;
            *(unsigned short*)(Xb + (cq * 4 + 2) * 144 + p * 2) = v.z;
            *(unsigned short*)(Xb + (cq * 4 + 3) * 144 + p * 2) = v.w;
        }
        __syncthreads();
#pragma unroll
        for (int kc = 0; kc < 2; ++kc) {
            const int kb = (kc * 32 + lkg * 8) * 2;
            bf16x8 af = *(const bf16x8*)(Xb + (wv * 16 + lrow) * 144 + kb);
#pragma unroll
            for (int n = 0; n < 4; ++n) {
                bf16x8 bf_ = *(const bf16x8*)(Xb + (n * 16 + lrow) * 144 + kb);
                acc[n] = __builtin_amdgcn_mfma_f32_16x16x32_bf16(af, bf_, acc[n], 0, 0, 0);
            }
        }
    }

    *(float4*)&sumb[pr][cq * 4] = (float4){csum[0], csum[1], csum[2], csum[3]};
    __syncthreads();
    float* pb = part + (size_t)blockIdx.x * 4160;
    if (tid < 64) {
        float s = 0.f;
#pragma unroll
        for (int r = 0; r < 16; ++r) s += sumb[r][tid];
        pb[4096 + tid] = s;
    }
#pragma unroll
    for (int n = 0; n < 4; ++n)
#pragma unroll
        for (int r = 0; r < 4; ++r)
            pb[(wv * 16 + lkg * 4 + r) * 64 + n * 16 + lrow] = acc[n][r];
}

__global__ void gram_reduce(const float* __restrict__ part, float* __restrict__ M)
{
    int e = blockIdx.x * 256 + threadIdx.x;
    if (e >= 4160) return;
    double s = 0.0;
    for (int p = 0; p < GRAM_BLOCKS; ++p) s += (double)part[(size_t)p * 4160 + e];
    M[e] = (float)s;
}

// Per-output-channel affine coefficients A,B such that out = A*(w_o . u) + B.
__global__ __launch_bounds__(256)
void stats_kernel(const float* __restrict__ M, const float* __restrict__ cw,
                  const float* __restrict__ cb, const float* __restrict__ bg,
                  const float* __restrict__ bb,
                  float* __restrict__ Aout, float* __restrict__ Bout)
{
    __shared__ float Ml[4160];
    const int tid = threadIdx.x;
    for (int e = tid; e < 4160; e += 256) Ml[e] = M[e];
    __syncthreads();
    float wr[64];
#pragma unroll
    for (int c = 0; c < 64; ++c) wr[c] = bf2f(f2bf(cw[tid * 64 + c]));
    float s1 = 0.f;
#pragma unroll
    for (int c = 0; c < 64; ++c) s1 = fmaf(wr[c], Ml[4096 + c], s1);
    float s2 = 0.f;
    for (int c = 0; c < 64; ++c) {
        const float* Mr = &Ml[c * 64];
        float t = 0.f;
#pragma unroll
        for (int d = 0; d < 64; ++d) t = fmaf(wr[d], Mr[d], t);
        s2 = fmaf(wr[c], t, s2);
    }
    const double invN = 1.0 / (double)NPIX;
    double cbo = (double)cb[tid];
    double mu = (double)s1 * invN + cbo;
    double ey2 = (double)s2 * invN + 2.0 * cbo * ((double)s1 * invN) + cbo * cbo;
    double var = ey2 - mu * mu;
    double A = (double)bg[tid] / sqrt(var + 1e-5);
    Aout[tid] = (float)A;
    Bout[tid] = (float)((double)bb[tid] + A * (cbo - mu));
}

// ---------------------------------------------------------------------------
// Fused 1x1 conv + BN apply via MFMA. Block = (b,w): D[96 h][256 o].
// Nontemporal f32x4 stores (302MB streaming output, never re-read).
// ---------------------------------------------------------------------------
__global__ __launch_bounds__(512, 2)
void conv_bn_kernel(const unsigned short* __restrict__ hh, const float* __restrict__ cw,
                    const float* __restrict__ Aarr, const float* __restrict__ Barr,
                    float* __restrict__ out)
{
    __shared__ alignas(16) unsigned char UsB[96 * 128];    // bf16 U, swizzled
    __shared__ alignas(16) unsigned char WtB[256 * 128];   // bf16 conv W, swizzled

    const int tid = threadIdx.x;
    const int b = blockIdx.x / 96, w = blockIdx.x % 96;

    for (int i4 = tid; i4 < 4096; i4 += 512) {
        int wrow = i4 >> 4, k4 = i4 & 15;
        float4 v = *(const float4*)(cw + (size_t)wrow * 64 + k4 * 4);
        ushort4 p; p.x = f2bf(v.x); p.y = f2bf(v.y); p.z = f2bf(v.z); p.w = f2bf(v.w);
        *(ushort4*)(WtB + wrow * 128 + ((k4 * 8) ^ ((wrow & 7) << 4))) = p;
    }
    for (int i = tid; i < 1536; i += 512) {
        int row = i >> 4, k4 = i & 15;   // row = h
        ushort4 p = *(const ushort4*)(hh + (((size_t)b * 96 + row) * 96 + w) * 64 + k4 * 4);
        *(ushort4*)(UsB + row * 128 + ((k4 * 8) ^ ((row & 7) << 4))) = p;
    }
    __syncthreads();

    const int wv = tid >> 6, lane = tid & 63;
    const int mbase = (wv >> 2) * 48, nbase = (wv & 3) * 64;
    const int lrow = lane & 15, lk = (lane >> 4) * 8;

    f32x4 acc[3][4];
#pragma unroll
    for (int m = 0; m < 3; ++m)
#pragma unroll
        for (int n = 0; n < 4; ++n)
            acc[m][n] = (f32x4){0.f, 0.f, 0.f, 0.f};

#pragma unroll
    for (int ks = 0; ks < 2; ++ks) {
        const int kb = (ks * 32 + lk) * 2;
        bf16x8 am[3], bn[4];
#pragma unroll
        for (int m = 0; m < 3; ++m) {
            int row = mbase + m * 16 + lrow;
            am[m] = *(const bf16x8*)(UsB + row * 128 + (kb ^ ((row & 7) << 4)));
        }
#pragma unroll
        for (int n = 0; n < 4; ++n) {
            int o = nbase + n * 16 + lrow;
            bn[n] = *(const bf16x8*)(WtB + o * 128 + (kb ^ ((o & 7) << 4)));
        }
#pragma unroll
        for (int m = 0; m < 3; ++m)
#pragma unroll
            for (int n = 0; n < 4; ++n)
                acc[m][n] = __builtin_amdgcn_mfma_f32_16x16x32_bf16(am[m], bn[n], acc[m][n], 0, 0, 0);
    }

    const int hbase0 = (lane >> 4) * 4;
#pragma unroll
    for (int n = 0; n < 4; ++n) {
        const int o = nbase + n * 16 + lrow;
        const float Ao = Aarr[o], Bo = Barr[o];
        float* obase = out + (((size_t)b * 256 + o) * 96 + w) * 96;
#pragma unroll
        for (int m = 0; m < 3; ++m) {
            const int h0 = mbase + m * 16 + hbase0;
            f32x4 res;
            res[0] = fmaf(Ao, acc[m][n][0], Bo);
            res[1] = fmaf(Ao, acc[m][n][1], Bo);
            res[2] = fmaf(Ao, acc[m][n][2], Bo);
            res[3] = fmaf(Ao, acc[m][n][3], Bo);
            __builtin_nontemporal_store(res, (f32x4*)(obase + h0));
        }
    }
}

extern "C" void kernel_launch(void* const* d_in, const int* in_sizes, int n_in,
                              void* d_out, int out_size, void* d_ws, size_t ws_size,
                              hipStream_t stream)
{
    const float* x       = (const float*)d_in[0];
    const float* v_wih_f = (const float*)d_in[1];
    const float* v_whh_f = (const float*)d_in[2];
    const float* v_bih_f = (const float*)d_in[3];
    const float* v_bhh_f = (const float*)d_in[4];
    const float* v_wih_b = (const float*)d_in[5];
    const float* v_whh_b = (const float*)d_in[6];
    const float* v_bih_b = (const float*)d_in[7];
    const float* v_bhh_b = (const float*)d_in[8];
    const float* h_wih_f = (const float*)d_in[9];
    const float* h_whh_f = (const float*)d_in[10];
    const float* h_bih_f = (const float*)d_in[11];
    const float* h_bhh_f = (const float*)d_in[12];
    const float* h_wih_b = (const float*)d_in[13];
    const float* h_whh_b = (const float*)d_in[14];
    const float* h_bih_b = (const float*)d_in[15];
    const float* h_bhh_b = (const float*)d_in[16];
    const float* conv_w  = (const float*)d_in[17];
    const float* conv_b  = (const float*)d_in[18];
    const float* bn_g    = (const float*)d_in[19];
    const float* bn_b    = (const float*)d_in[20];
    float* out = (float*)d_out;

    // d_out (302 MB) doubles as scratch before conv_bn rewrites all of it:
    //   front 37.7 MB: xT (bf16 [chain=(b,w)][t=h][c]) — dead after pass 1
    //   @64 MB: gram partials (256 x 4160 f32 = 4.3 MB)
    //   tail 37.7 MB: v (bf16 [chain=(b,h)][t=w][c])  — vertical LSTM output
    const size_t v_elems = (size_t)Bn * Hn * Wn * 64;   // 18,874,368 bf16
    unsigned short* v_buf = (unsigned short*)(out + (size_t)out_size) - v_elems;
    unsigned short* xT = (unsigned short*)d_out;
    float* part = (float*)((char*)d_out + (64u << 20));

    // workspace layout
    unsigned short* hh = (unsigned short*)d_ws;                       // bf16 [B,H,W,64]
    char* wsb = (char*)d_ws;
    float* M    = (float*)(wsb + 37748736);                           // 4160 f32
    float* Aarr = M + 4160;
    float* Barr = Aarr + 256;

    // vertical pass: transpose x, then fused projection+recurrence
    transpose_x<<<3072, 256, 0, stream>>>(x, xT);
    lstm_fused<1><<<384, 128, 0, stream>>>(xT, v_wih_f, v_whh_f, v_bih_f, v_bhh_f,
                                           v_wih_b, v_whh_b, v_bih_b, v_bhh_b, v_buf);
    // horizontal pass: v is already [chain][t][c]
    lstm_fused<0><<<384, 128, 0, stream>>>(v_buf, h_wih_f, h_whh_f, h_bih_f, h_bhh_f,
                                           h_wih_b, h_whh_b, h_bih_b, h_bhh_b, hh);
    // conv + BN (affine-folded via Gram-matrix stats)
    gram_partial<<<GRAM_BLOCKS, 256, 0, stream>>>(hh, part);
    gram_reduce<<<17, 256, 0, stream>>>(part, M);
    stats_kernel<<<1, 256, 0, stream>>>(M, conv_w, conv_b, bn_g, bn_b, Aarr, Barr);
    conv_bn_kernel<<<3072, 512, 0, stream>>>(hh, conv_w, Aarr, Barr, out);
}

// Round 17
// 336.778 us; speedup vs baseline: 1.6217x; 1.0072x over previous
//
#include <hip/hip_runtime.h>
#include <stdint.h>

#define DI __device__ __forceinline__

constexpr int Bn = 32, Cc = 64, Wn = 96, Hn = 96, Ln = 32, NG = 128, OUTC = 256;
constexpr int SEQ = 96;
constexpr long long NPIX = (long long)Bn * Wn * Hn;   // 294912
constexpr int GRAM_BLOCKS = 256;
constexpr int PIX_PER_BLOCK = (int)(NPIX / GRAM_BLOCKS); // 1152

typedef __attribute__((ext_vector_type(8))) short bf16x8;
typedef __attribute__((ext_vector_type(4))) float f32x4;

constexpr float LOG2E  = 1.44269504088896340736f;
constexpr float TWOL2E = 2.88539008177792681472f;

DI float exp2_(float x) { return __builtin_amdgcn_exp2f(x); }   // v_exp_f32
DI float rcp_(float x)  { return __builtin_amdgcn_rcpf(x); }    // v_rcp_f32 (~1ulp)
DI float bf2f(unsigned short u) { return __uint_as_float(((unsigned)u) << 16); }
DI unsigned short f2bf(float f) {
    unsigned u = __float_as_uint(f);
    u += 0x7FFFu + ((u >> 16) & 1u);   // RNE
    return (unsigned short)(u >> 16);
}

// ---------------------------------------------------------------------------
// x transpose: [B,C,W,H] f32 -> xT[chain=(b,w)][t=h][c] bf16.
// ---------------------------------------------------------------------------
__global__ __launch_bounds__(256)
void transpose_x(const float* __restrict__ x, unsigned short* __restrict__ xT)
{
    __shared__ alignas(16) unsigned char xs[96 * 128];
    const int tid = threadIdx.x;
    const int b = blockIdx.x / 96, q = blockIdx.x % 96;
    for (int i = tid; i < 1536; i += 256) {
        int c = i / 24, h4 = i - c * 24;
        float4 v = *(const float4*)(x + (((size_t)b * 64 + c) * 96 + q) * 96 + 4 * h4);
        float vv[4] = {v.x, v.y, v.z, v.w};
#pragma unroll
        for (int j = 0; j < 4; ++j) {
            int h = 4 * h4 + j;
            *(unsigned short*)(xs + h * 128 + ((c * 2) ^ ((h & 7) << 4))) = f2bf(vv[j]);
        }
    }
    __syncthreads();
    unsigned short* ob = xT + (size_t)blockIdx.x * 6144;
    for (int i = tid; i < 768; i += 256) {
        int row = i >> 3, k8 = i & 7;
        bf16x8 p = *(const bf16x8*)(xs + row * 128 + ((k8 * 16) ^ ((row & 7) << 4)));
        *(bf16x8*)(ob + (size_t)i * 8) = p;
    }
}

// ---------------------------------------------------------------------------
// FUSED BiLSTM (R17 = R16 + relaxed per-step barrier). R16 evidence: 2-wave
// split cut per-wave issue ~half yet wall/step stayed ~2020cyc -> the
// __syncthreads each step compiles to s_waitcnt vmcnt(0) lgkmcnt(0) +
// s_barrier (m97 drain), exposing the per-step global store ack + xT
// prefetch latency ~1200cyc x 96 steps. Fix (T4 principle): h is the ONLY
// cross-wave datum and lives in LDS -> ds_write, s_waitcnt lgkmcnt(0),
// raw s_barrier, sched_barrier(0). Global stores/prefetch stay in flight
// across the barrier (never drain vmcnt in the main loop).
// Wave wv owns gate tiles {wv,2+wv,4+wv,6+wv} = cells wv*16..+15
// (self-contained cell update: 12 MFMA, 40 trans/lane/step).
// ---------------------------------------------------------------------------
#define FLOAD(XA, XB, STI)                                                     \
    if ((STI) < 96) {                                                          \
        const int tl_ = dir ? 95 - (STI) : (STI);                              \
        XA = *(const bf16x8*)(xTb + (size_t)tl_ * 64);                         \
        XB = *(const bf16x8*)(xTb + (size_t)tl_ * 64 + 32);                    \
    }

#define PPROJ(XA, XB)                                                          \
    _Pragma("unroll")                                                          \
    for (int g_ = 0; g_ < 4; ++g_) {                                           \
        f32x4 tp_ = __builtin_amdgcn_mfma_f32_16x16x32_bf16(ax0[g_], XA, bc[g_], 0, 0, 0); \
        xac[g_] = __builtin_amdgcn_mfma_f32_16x16x32_bf16(ax1[g_], XB, tp_, 0, 0, 0);      \
    }

#define RSTEP(STI)                                                             \
    {                                                                          \
        const bf16x8 hu = *(const bf16x8*)(hcur + n_ * 80 + rg * 16);          \
        f32x4 ac_[4];                                                          \
        _Pragma("unroll")                                                      \
        for (int g_ = 0; g_ < 4; ++g_)                                         \
            ac_[g_] = __builtin_amdgcn_mfma_f32_16x16x32_bf16(ah[g_], hu, xac[g_], 0, 0, 0); \
        unsigned short hs[4];                                                  \
        _Pragma("unroll")                                                      \
        for (int j = 0; j < 4; ++j) {                                          \
            const float iv = rcp_(1.f + exp2_(-ac_[0][j]));                    \
            const float fv = rcp_(1.f + exp2_(-ac_[1][j]));                    \
            const float gr = rcp_(1.f + exp2_(-ac_[2][j]));                    \
            const float gv = fmaf(2.f, gr, -1.f);                              \
            const float ov = rcp_(1.f + exp2_(-ac_[3][j]));                    \
            cc[j] = fmaf(fv, cc[j], iv * gv);                                  \
            const float r_ = rcp_(exp2_(cc[j] * TWOL2E) + 1.f);                \
            const float t2 = -2.f * ov;                                        \
            hs[j] = f2bf(fmaf(t2, r_, ov));                                    \
        }                                                                      \
        ushort4 hp; hp.x = hs[0]; hp.y = hs[1]; hp.z = hs[2]; hp.w = hs[3];    \
        *(ushort4*)(hnxt + n_ * 80 + wv * 32 + rg * 8) = hp;                   \
        *(ushort4*)optr = hp;                                                  \
        optr += odelta;                                                        \
        asm volatile("s_waitcnt lgkmcnt(0)" ::: "memory");                     \
        __builtin_amdgcn_s_barrier();                                          \
        __builtin_amdgcn_sched_barrier(0);                                     \
        { unsigned char* t_ = hcur; hcur = hnxt; hnxt = t_; }                  \
    }

template<int VERT>
__global__ __launch_bounds__(128, 1)
void lstm_fused(const unsigned short* __restrict__ xT,
                const float* __restrict__ wih_f, const float* __restrict__ whh_f,
                const float* __restrict__ bih_f, const float* __restrict__ bhh_f,
                const float* __restrict__ wih_b, const float* __restrict__ whh_b,
                const float* __restrict__ bih_b, const float* __restrict__ bhh_b,
                unsigned short* __restrict__ outU)
{
    __shared__ alignas(16) unsigned char hbuf[2][16 * 80];  // h[chain][32cells] bf16, 80B stride

    const int tid = threadIdx.x;
    const int wv = tid >> 6, lane = tid & 63;
    const int dir = blockIdx.x & 1, group = blockIdx.x >> 1;   // group in [0,192)
    const int n_ = lane & 15, rg = lane >> 4;
    const int chain = group * 16 + n_;
    const int b = group / 6;
    const int q = (group % 6) * 16 + n_;

    const float* wih = dir ? wih_b : wih_f;
    const float* whh = dir ? whh_b : whh_f;
    const float* bih = dir ? bih_b : bih_f;
    const float* bhh = dir ? bhh_b : bhh_f;

    // Wave wv owns gate tiles tt = 2*g_ + wv (g_ = i,f,g,o), cells wv*16..+15.
    // Weights pre-scaled into exp2 domain (g-gate by 2*log2e). Fragment
    // mapping refcheck'd R9-R16: lane (n_, rg): row = tt*16+n_, k = rg*8..+8.
    bf16x8 ah[4], ax0[4], ax1[4];
    f32x4 bc[4];
#pragma unroll
    for (int g_ = 0; g_ < 4; ++g_) {
        const int tt = 2 * g_ + wv;
        const float sc = (g_ == 2) ? TWOL2E : LOG2E;
        const float* sh = whh + (size_t)(tt * 16 + n_) * 32 + rg * 8;
        const float* sx = wih + (size_t)(tt * 16 + n_) * 64 + rg * 8;
        float4 h0 = *(const float4*)sh, h1 = *(const float4*)(sh + 4);
        float4 x0 = *(const float4*)sx, x1 = *(const float4*)(sx + 4);
        float4 x2 = *(const float4*)(sx + 32), x3 = *(const float4*)(sx + 36);
        ah[g_][0] = (short)f2bf(sc * h0.x); ah[g_][1] = (short)f2bf(sc * h0.y);
        ah[g_][2] = (short)f2bf(sc * h0.z); ah[g_][3] = (short)f2bf(sc * h0.w);
        ah[g_][4] = (short)f2bf(sc * h1.x); ah[g_][5] = (short)f2bf(sc * h1.y);
        ah[g_][6] = (short)f2bf(sc * h1.z); ah[g_][7] = (short)f2bf(sc * h1.w);
        ax0[g_][0] = (short)f2bf(sc * x0.x); ax0[g_][1] = (short)f2bf(sc * x0.y);
        ax0[g_][2] = (short)f2bf(sc * x0.z); ax0[g_][3] = (short)f2bf(sc * x0.w);
        ax0[g_][4] = (short)f2bf(sc * x1.x); ax0[g_][5] = (short)f2bf(sc * x1.y);
        ax0[g_][6] = (short)f2bf(sc * x1.z); ax0[g_][7] = (short)f2bf(sc * x1.w);
        ax1[g_][0] = (short)f2bf(sc * x2.x); ax1[g_][1] = (short)f2bf(sc * x2.y);
        ax1[g_][2] = (short)f2bf(sc * x2.z); ax1[g_][3] = (short)f2bf(sc * x2.w);
        ax1[g_][4] = (short)f2bf(sc * x3.x); ax1[g_][5] = (short)f2bf(sc * x3.y);
        ax1[g_][6] = (short)f2bf(sc * x3.z); ax1[g_][7] = (short)f2bf(sc * x3.w);
#pragma unroll
        for (int j = 0; j < 4; ++j) {
            const int g = tt * 16 + rg * 4 + j;
            bc[g_][j] = sc * (bih[g] + bhh[g]);
        }
    }

    const unsigned short* xTb = xT + (size_t)chain * 6144 + rg * 8;

    // running output pointer; this wave stores its s-group's pack only
    const int t0 = dir ? 95 : 0;
    const size_t o0 = VERT ? ((((size_t)b * 96 + t0) * 96 + q) * 64)
                           : ((((size_t)b * 96 + q) * 96 + t0) * 64);
    unsigned short* optr = outU + o0 + dir * 32 + wv * 16 + rg * 4;
    const ptrdiff_t odelta = (ptrdiff_t)(dir ? -1 : 1) * (VERT ? 6144 : 64);

    // zero initial h (buffer 0 only); both waves participate
    for (int i = tid; i < 320; i += 128) ((unsigned*)hbuf[0])[i] = 0u;

    unsigned char* hcur = hbuf[0];
    unsigned char* hnxt = hbuf[1];

    float cc[4] = {0.f, 0.f, 0.f, 0.f};
    f32x4 xac[4];
    bf16x8 xa0, xb0, xa1, xb1, xa2, xb2;
    FLOAD(xa0, xb0, 0)
    FLOAD(xa1, xb1, 1)
    PPROJ(xa0, xb0)
    __syncthreads();

    for (int st = 0; st < 96; st += 3) {
        FLOAD(xa2, xb2, st + 2)
        RSTEP(st)
        PPROJ(xa1, xb1)
        FLOAD(xa0, xb0, st + 3)
        RSTEP(st + 1)
        PPROJ(xa2, xb2)
        FLOAD(xa1, xb1, st + 4)
        RSTEP(st + 2)
        PPROJ(xa0, xb0)
    }
}

// ---------------------------------------------------------------------------
// Partial Gram (64x64) + channel-sum via MFMA (R14/R15, passed). Symmetry =>
// A and B fragments read the SAME transposed LDS image XsT[c][p] (144B rows).
// ---------------------------------------------------------------------------
__global__ __launch_bounds__(256, 2)
void gram_partial(const unsigned short* __restrict__ hh, float* __restrict__ part)
{
    __shared__ alignas(16) unsigned char xsT[2][64 * 144];  // bf16 [c][p], 144B rows
    __shared__ float sumb[16][64];

    const int tid = threadIdx.x;
    const int wv = tid >> 6, lane = tid & 63;
    const int lrow = lane & 15, lkg = lane >> 4;
    const int cq = tid & 15, pr = tid >> 4;

    float csum[4] = {0.f, 0.f, 0.f, 0.f};
    f32x4 acc[4];
#pragma unroll
    for (int n = 0; n < 4; ++n) acc[n] = (f32x4){0.f, 0.f, 0.f, 0.f};

    const size_t pix0 = (size_t)blockIdx.x * PIX_PER_BLOCK;

    for (int tile = 0; tile < PIX_PER_BLOCK / 64; ++tile) {
        unsigned char* Xb = xsT[tile & 1];
#pragma unroll
        for (int r = 0; r < 4; ++r) {
            const int p = pr + r * 16;
            ushort4 v = *(const ushort4*)(hh + (pix0 + (size_t)tile * 64 + p) * 64 + cq * 4);
            csum[0] += bf2f(v.x); csum[1] += bf2f(v.y);
            csum[2] += bf2f(v.z); csum[3] += bf2f(v.w);
            *(unsigned short*)(Xb + (cq * 4 + 0) * 144 + p * 2) = v.x;
            *(unsigned short*)(Xb + (cq * 4 + 1) * 144 + p * 2) = v.y;
            *(unsigned short*)(Xb + (cq * 4 + 2) * 144 + p * 2) = v.z;
            *(unsigned short*)(Xb + (cq * 4 + 3) * 144 + p * 2) = v.w;
        }
        __syncthreads();
#pragma unroll
        for (int kc = 0; kc < 2; ++kc) {
            const int kb = (kc * 32 + lkg * 8) * 2;
            bf16x8 af = *(const bf16x8*)(Xb + (wv * 16 + lrow) * 144 + kb);
#pragma unroll
            for (int n = 0; n < 4; ++n) {
                bf16x8 bf_ = *(const bf16x8*)(Xb + (n * 16 + lrow) * 144 + kb);
                acc[n] = __builtin_amdgcn_mfma_f32_16x16x32_bf16(af, bf_, acc[n], 0, 0, 0);
            }
        }
    }

    *(float4*)&sumb[pr][cq * 4] = (float4){csum[0], csum[1], csum[2], csum[3]};
    __syncthreads();
    float* pb = part + (size_t)blockIdx.x * 4160;
    if (tid < 64) {
        float s = 0.f;
#pragma unroll
        for (int r = 0; r < 16; ++r) s += sumb[r][tid];
        pb[4096 + tid] = s;
    }
#pragma unroll
    for (int n = 0; n < 4; ++n)
#pragma unroll
        for (int r = 0; r < 4; ++r)
            pb[(wv * 16 + lkg * 4 + r) * 64 + n * 16 + lrow] = acc[n][r];
}

__global__ void gram_reduce(const float* __restrict__ part, float* __restrict__ M)
{
    int e = blockIdx.x * 256 + threadIdx.x;
    if (e >= 4160) return;
    double s = 0.0;
    for (int p = 0; p < GRAM_BLOCKS; ++p) s += (double)part[(size_t)p * 4160 + e];
    M[e] = (float)s;
}

// Per-output-channel affine coefficients A,B such that out = A*(w_o . u) + B.
__global__ __launch_bounds__(256)
void stats_kernel(const float* __restrict__ M, const float* __restrict__ cw,
                  const float* __restrict__ cb, const float* __restrict__ bg,
                  const float* __restrict__ bb,
                  float* __restrict__ Aout, float* __restrict__ Bout)
{
    __shared__ float Ml[4160];
    const int tid = threadIdx.x;
    for (int e = tid; e < 4160; e += 256) Ml[e] = M[e];
    __syncthreads();
    float wr[64];
#pragma unroll
    for (int c = 0; c < 64; ++c) wr[c] = bf2f(f2bf(cw[tid * 64 + c]));
    float s1 = 0.f;
#pragma unroll
    for (int c = 0; c < 64; ++c) s1 = fmaf(wr[c], Ml[4096 + c], s1);
    float s2 = 0.f;
    for (int c = 0; c < 64; ++c) {
        const float* Mr = &Ml[c * 64];
        float t = 0.f;
#pragma unroll
        for (int d = 0; d < 64; ++d) t = fmaf(wr[d], Mr[d], t);
        s2 = fmaf(wr[c], t, s2);
    }
    const double invN = 1.0 / (double)NPIX;
    double cbo = (double)cb[tid];
    double mu = (double)s1 * invN + cbo;
    double ey2 = (double)s2 * invN + 2.0 * cbo * ((double)s1 * invN) + cbo * cbo;
    double var = ey2 - mu * mu;
    double A = (double)bg[tid] / sqrt(var + 1e-5);
    Aout[tid] = (float)A;
    Bout[tid] = (float)((double)bb[tid] + A * (cbo - mu));
}

// ---------------------------------------------------------------------------
// Fused 1x1 conv + BN apply via MFMA. Block = (b,w): D[96 h][256 o].
// Nontemporal f32x4 stores (302MB streaming output, never re-read).
// ---------------------------------------------------------------------------
__global__ __launch_bounds__(512, 2)
void conv_bn_kernel(const unsigned short* __restrict__ hh, const float* __restrict__ cw,
                    const float* __restrict__ Aarr, const float* __restrict__ Barr,
                    float* __restrict__ out)
{
    __shared__ alignas(16) unsigned char UsB[96 * 128];    // bf16 U, swizzled
    __shared__ alignas(16) unsigned char WtB[256 * 128];   // bf16 conv W, swizzled

    const int tid = threadIdx.x;
    const int b = blockIdx.x / 96, w = blockIdx.x % 96;

    for (int i4 = tid; i4 < 4096; i4 += 512) {
        int wrow = i4 >> 4, k4 = i4 & 15;
        float4 v = *(const float4*)(cw + (size_t)wrow * 64 + k4 * 4);
        ushort4 p; p.x = f2bf(v.x); p.y = f2bf(v.y); p.z = f2bf(v.z); p.w = f2bf(v.w);
        *(ushort4*)(WtB + wrow * 128 + ((k4 * 8) ^ ((wrow & 7) << 4))) = p;
    }
    for (int i = tid; i < 1536; i += 512) {
        int row = i >> 4, k4 = i & 15;   // row = h
        ushort4 p = *(const ushort4*)(hh + (((size_t)b * 96 + row) * 96 + w) * 64 + k4 * 4);
        *(ushort4*)(UsB + row * 128 + ((k4 * 8) ^ ((row & 7) << 4))) = p;
    }
    __syncthreads();

    const int wv = tid >> 6, lane = tid & 63;
    const int mbase = (wv >> 2) * 48, nbase = (wv & 3) * 64;
    const int lrow = lane & 15, lk = (lane >> 4) * 8;

    f32x4 acc[3][4];
#pragma unroll
    for (int m = 0; m < 3; ++m)
#pragma unroll
        for (int n = 0; n < 4; ++n)
            acc[m][n] = (f32x4){0.f, 0.f, 0.f, 0.f};

#pragma unroll
    for (int ks = 0; ks < 2; ++ks) {
        const int kb = (ks * 32 + lk) * 2;
        bf16x8 am[3], bn[4];
#pragma unroll
        for (int m = 0; m < 3; ++m) {
            int row = mbase + m * 16 + lrow;
            am[m] = *(const bf16x8*)(UsB + row * 128 + (kb ^ ((row & 7) << 4)));
        }
#pragma unroll
        for (int n = 0; n < 4; ++n) {
            int o = nbase + n * 16 + lrow;
            bn[n] = *(const bf16x8*)(WtB + o * 128 + (kb ^ ((o & 7) << 4)));
        }
#pragma unroll
        for (int m = 0; m < 3; ++m)
#pragma unroll
            for (int n = 0; n < 4; ++n)
                acc[m][n] = __builtin_amdgcn_mfma_f32_16x16x32_bf16(am[m], bn[n], acc[m][n], 0, 0, 0);
    }

    const int hbase0 = (lane >> 4) * 4;
#pragma unroll
    for (int n = 0; n < 4; ++n) {
        const int o = nbase + n * 16 + lrow;
        const float Ao = Aarr[o], Bo = Barr[o];
        float* obase = out + (((size_t)b * 256 + o) * 96 + w) * 96;
#pragma unroll
        for (int m = 0; m < 3; ++m) {
            const int h0 = mbase + m * 16 + hbase0;
            f32x4 res;
            res[0] = fmaf(Ao, acc[m][n][0], Bo);
            res[1] = fmaf(Ao, acc[m][n][1], Bo);
            res[2] = fmaf(Ao, acc[m][n][2], Bo);
            res[3] = fmaf(Ao, acc[m][n][3], Bo);
            __builtin_nontemporal_store(res, (f32x4*)(obase + h0));
        }
    }
}

extern "C" void kernel_launch(void* const* d_in, const int* in_sizes, int n_in,
                              void* d_out, int out_size, void* d_ws, size_t ws_size,
                              hipStream_t stream)
{
    const float* x       = (const float*)d_in[0];
    const float* v_wih_f = (const float*)d_in[1];
    const float* v_whh_f = (const float*)d_in[2];
    const float* v_bih_f = (const float*)d_in[3];
    const float* v_bhh_f = (const float*)d_in[4];
    const float* v_wih_b = (const float*)d_in[5];
    const float* v_whh_b = (const float*)d_in[6];
    const float* v_bih_b = (const float*)d_in[7];
    const float* v_bhh_b = (const float*)d_in[8];
    const float* h_wih_f = (const float*)d_in[9];
    const float* h_whh_f = (const float*)d_in[10];
    const float* h_bih_f = (const float*)d_in[11];
    const float* h_bhh_f = (const float*)d_in[12];
    const float* h_wih_b = (const float*)d_in[13];
    const float* h_whh_b = (const float*)d_in[14];
    const float* h_bih_b = (const float*)d_in[15];
    const float* h_bhh_b = (const float*)d_in[16];
    const float* conv_w  = (const float*)d_in[17];
    const float* conv_b  = (const float*)d_in[18];
    const float* bn_g    = (const float*)d_in[19];
    const float* bn_b    = (const float*)d_in[20];
    float* out = (float*)d_out;

    // d_out (302 MB) doubles as scratch before conv_bn rewrites all of it:
    //   front 37.7 MB: xT (bf16 [chain=(b,w)][t=h][c]) — dead after pass 1
    //   @64 MB: gram partials (256 x 4160 f32 = 4.3 MB)
    //   tail 37.7 MB: v (bf16 [chain=(b,h)][t=w][c])  — vertical LSTM output
    const size_t v_elems = (size_t)Bn * Hn * Wn * 64;   // 18,874,368 bf16
    unsigned short* v_buf = (unsigned short*)(out + (size_t)out_size) - v_elems;
    unsigned short* xT = (unsigned short*)d_out;
    float* part = (float*)((char*)d_out + (64u << 20));

    // workspace layout
    unsigned short* hh = (unsigned short*)d_ws;                       // bf16 [B,H,W,64]
    char* wsb = (char*)d_ws;
    float* M    = (float*)(wsb + 37748736);                           // 4160 f32
    float* Aarr = M + 4160;
    float* Barr = Aarr + 256;

    // vertical pass: transpose x, then fused projection+recurrence
    transpose_x<<<3072, 256, 0, stream>>>(x, xT);
    lstm_fused<1><<<384, 128, 0, stream>>>(xT, v_wih_f, v_whh_f, v_bih_f, v_bhh_f,
                                           v_wih_b, v_whh_b, v_bih_b, v_bhh_b, v_buf);
    // horizontal pass: v is already [chain][t][c]
    lstm_fused<0><<<384, 128, 0, stream>>>(v_buf, h_wih_f, h_whh_f, h_bih_f, h_bhh_f,
                                           h_wih_b, h_whh_b, h_bih_b, h_bhh_b, hh);
    // conv + BN (affine-folded via Gram-matrix stats)
    gram_partial<<<GRAM_BLOCKS, 256, 0, stream>>>(hh, part);
    gram_reduce<<<17, 256, 0, stream>>>(part, M);
    stats_kernel<<<1, 256, 0, stream>>>(M, conv_w, conv_b, bn_g, bn_b, Aarr, Barr);
    conv_bn_kernel<<<3072, 512, 0, stream>>>(hh, conv_w, Aarr, Barr, out);
}